// Round 1
// baseline (3030.451 us; speedup 1.0000x reference)
//
#include <hip/hip_runtime.h>
#include <math.h>

// ---------------- problem constants ----------------
constexpr int cN  = 50000;
constexpr int cE  = 600000;
constexpr int cR  = 64;
constexpr int cV  = cN - cR;     // 49936
constexpr int cNF = 9;
constexpr int cIN = 41;          // 9 + 32

// ---------------- ws layout (floats) ----------------
// const region sub-offsets
constexpr int K_GATES = 0;    // 3
constexpr int K_WTS   = 3;    // 3
constexpr int K_LOOP1 = 6;    // 3*4  self-loop alpha_e, layer1
constexpr int K_LOOP2 = 18;   // 3    self-loop alpha_e, layer2
constexpr int K_VE1   = 32;   // 3*8*4  (We1 @ a_e1) per head
constexpr int K_VE2   = 128;  // 3*8    (We2 @ a_e2)
constexpr int K_EASUM = 160;  // 3*8    column sums of ea

constexpr size_t OFF_X0  = 1024;
constexpr size_t OFF_H   = OFF_X0  + (size_t)cN*cIN;     // h1 then h2
constexpr size_t OFF_OUT = OFF_H   + (size_t)cN*128;     // out_num -> out1 -> out_num2
constexpr size_t OFF_ACC = OFF_OUT + (size_t)cN*128;     // accumulated over 3 types
constexpr size_t OFF_EV  = OFF_ACC + (size_t)cN*128;     // per-edge exp(alpha), 4/edge
constexpr size_t OFF_DEN = OFF_EV  + (size_t)(cE+cN)*4;  // softmax denominators
constexpr size_t OFF_AS  = OFF_DEN + (size_t)cN*4;       // alpha_src per node
constexpr size_t OFF_AD  = OFF_AS  + (size_t)cN*4;       // alpha_dst per node
constexpr size_t OFF_ES  = OFF_AD  + (size_t)cN*4;       // exp(scores) for pooling
constexpr size_t OFF_PN  = OFF_ES  + (size_t)cN;         // pooled numerator 64*128
constexpr size_t OFF_DENP= OFF_PN  + (size_t)cR*128;     // pool denominators 64

// ---------------- small setup kernels ----------------
__global__ void k_setup(const float* __restrict__ etg, const float* __restrict__ eta,
                        const float* __restrict__ We1, const float* __restrict__ ae1,
                        const float* __restrict__ We2, const float* __restrict__ ae2,
                        float* __restrict__ cst, float* __restrict__ dout){
  int t = threadIdx.x; // 128 threads
  if (t < 3){
    cst[K_GATES+t] = 1.f/(1.f+expf(-etg[t]));
    float m = fmaxf(fmaxf(eta[0],eta[1]),eta[2]);
    float e0=expf(eta[0]-m), e1=expf(eta[1]-m), e2=expf(eta[2]-m);
    cst[K_WTS+t] = expf(eta[t]-m)/(e0+e1+e2);
    dout[1024+t] = eta[t];       // second tuple output
  }
  if (t < 96){ // ve1[i][k][h] = sum_c We1[i,k,h*32+c]*ae1[i,h,c]
    int i = t >> 5, k = (t>>2)&7, h = t&3;
    const float* w = We1 + ((size_t)(i*8+k))*128 + h*32;
    const float* a = ae1 + (i*4+h)*32;
    float s = 0.f;
    for (int c=0;c<32;c++) s += w[c]*a[c];
    cst[K_VE1 + t] = s;          // t == (i*8+k)*4+h
  }
  if (t < 24){ // ve2[i][k] = sum_c We2[i,k,c]*ae2[i,c]
    int i = t >> 3, k = t & 7;
    const float* w = We2 + ((size_t)(i*8+k))*128;
    const float* a = ae2 + i*128;
    float s = 0.f;
    for (int c=0;c<128;c++) s += w[c]*a[c];
    cst[K_VE2 + t] = s;
  }
}

__global__ void k_eamean(const float* __restrict__ ea0, const float* __restrict__ ea1,
                         const float* __restrict__ ea2, float* __restrict__ cst){
  int i = blockIdx.y;
  const float* ea = (i==0)?ea0:(i==1)?ea1:ea2;
  float s[8]; 
  #pragma unroll
  for (int k=0;k<8;k++) s[k]=0.f;
  for (int e = blockIdx.x*blockDim.x + threadIdx.x; e < cE; e += gridDim.x*blockDim.x){
    const float4* p = (const float4*)(ea + (size_t)e*8);
    float4 a = p[0], b = p[1];
    s[0]+=a.x; s[1]+=a.y; s[2]+=a.z; s[3]+=a.w;
    s[4]+=b.x; s[5]+=b.y; s[6]+=b.z; s[7]+=b.w;
  }
  for (int m=1;m<64;m<<=1){
    #pragma unroll
    for (int k=0;k<8;k++) s[k] += __shfl_xor(s[k], m, 64);
  }
  if ((threadIdx.x & 63) == 0){
    #pragma unroll
    for (int k=0;k<8;k++) atomicAdd(&cst[K_EASUM + i*8 + k], s[k]);
  }
}

__global__ void k_loopconsts(float* __restrict__ cst){
  int t = threadIdx.x;
  if (t < 12){
    int i=t>>2, h=t&3;
    float s=0.f;
    for (int k=0;k<8;k++) s += (cst[K_EASUM+i*8+k]/(float)cE)*cst[K_VE1+(i*8+k)*4+h];
    cst[K_LOOP1+t] = cst[K_GATES+i]*s;
  } else if (t < 15){
    int i=t-12; float s=0.f;
    for (int k=0;k<8;k++) s += (cst[K_EASUM+i*8+k]/(float)cE)*cst[K_VE2+i*8+k];
    cst[K_LOOP2+i] = cst[K_GATES+i]*s;
  }
}

__global__ void k_x0(const float* __restrict__ nf, const float* __restrict__ te,
                     const int* __restrict__ nt, float* __restrict__ x0){
  int n = blockIdx.x, j = threadIdx.x;
  if (j >= cIN) return;
  float v = (j < cNF) ? nf[(size_t)n*cNF + j] : te[nt[n]*32 + (j-cNF)];
  x0[(size_t)n*cIN + j] = v;
}

// ---------------- GEMM: C[n][ch*64+c] = sum_k A[n][k]*B[k][128-wide col ch] ----------------
// block: 256 threads, tile 64 rows x 64 cols (grid.y = c-half), 4x4 register tile.
template<int K, int KS>
__global__ __launch_bounds__(256) void k_gemm(const float* __restrict__ A,
                                              const float* __restrict__ B,
                                              float* __restrict__ C, int nrows){
  __shared__ float sA[64][KS];
  __shared__ float sB[K][64];
  const int tid = threadIdx.x;
  const int nb = blockIdx.x * 64;
  const int ch = blockIdx.y;
  for (int idx = tid; idx < 64*K; idx += 256){
    int n = idx / K, k = idx - n*K;
    int row = nb + n; if (row >= nrows) row = nrows - 1;
    sA[n][k] = A[(size_t)row*K + k];
  }
  for (int idx = tid; idx < K*64; idx += 256){
    int k = idx >> 6, c = idx & 63;
    sB[k][c] = B[k*128 + ch*64 + c];
  }
  __syncthreads();
  const int cg = tid & 15, ng = tid >> 4;
  const int c0 = cg*4, n0 = ng*4;
  float acc[4][4] = {};
  int k = 0;
  for (; k + 4 <= K; k += 4){
    float4 a4[4], w4[4];
    #pragma unroll
    for (int ii=0; ii<4; ii++) a4[ii] = *(const float4*)&sA[n0+ii][k];
    #pragma unroll
    for (int kk=0; kk<4; kk++) w4[kk] = *(const float4*)&sB[k+kk][c0];
    const float* ap = (const float*)a4;  // [ii][kk]
    const float* wp = (const float*)w4;  // [kk][jj]
    #pragma unroll
    for (int ii=0; ii<4; ii++)
      #pragma unroll
      for (int kk=0; kk<4; kk++)
        #pragma unroll
        for (int jj=0; jj<4; jj++)
          acc[ii][jj] += ap[ii*4+kk]*wp[kk*4+jj];
  }
  for (; k < K; k++){
    float4 wv = *(const float4*)&sB[k][c0];
    #pragma unroll
    for (int ii=0; ii<4; ii++){
      float a = sA[n0+ii][k];
      acc[ii][0]+=a*wv.x; acc[ii][1]+=a*wv.y; acc[ii][2]+=a*wv.z; acc[ii][3]+=a*wv.w;
    }
  }
  #pragma unroll
  for (int ii=0; ii<4; ii++){
    int row = nb + n0 + ii;
    if (row < nrows){
      float4 v = make_float4(acc[ii][0],acc[ii][1],acc[ii][2],acc[ii][3]);
      *(float4*)&C[(size_t)row*128 + ch*64 + c0] = v;
    }
  }
}

// ---------------- per-node attention logit pieces ----------------
__global__ void k_anode1(const float* __restrict__ h, const float* __restrict__ as_,
                         const float* __restrict__ ad_, float* __restrict__ alphas,
                         float* __restrict__ alphad){
  int n = blockIdx.x, l = threadIdx.x; // 64 threads
  float h0 = h[(size_t)n*128 + l], h1 = h[(size_t)n*128 + 64 + l];
  float s0 = h0*as_[l], s1 = h1*as_[64+l];
  float d0 = h0*ad_[l], d1 = h1*ad_[64+l];
  for (int m=1;m<32;m<<=1){
    s0 += __shfl_xor(s0,m,64); s1 += __shfl_xor(s1,m,64);
    d0 += __shfl_xor(d0,m,64); d1 += __shfl_xor(d1,m,64);
  }
  if ((l&31)==0){
    int hh = l>>5; // 0 or 1
    alphas[n*4+hh]   = s0; alphas[n*4+2+hh] = s1;
    alphad[n*4+hh]   = d0; alphad[n*4+2+hh] = d1;
  }
}

__global__ void k_anode2(const float* __restrict__ h, const float* __restrict__ as_,
                         const float* __restrict__ ad_, float* __restrict__ alphas,
                         float* __restrict__ alphad){
  int n = blockIdx.x, l = threadIdx.x;
  float h0 = h[(size_t)n*128+l], h1 = h[(size_t)n*128+64+l];
  float s = h0*as_[l] + h1*as_[64+l];
  float d = h0*ad_[l] + h1*ad_[64+l];
  for (int m=1;m<64;m<<=1){ s += __shfl_xor(s,m,64); d += __shfl_xor(d,m,64); }
  if (l==0){ alphas[n] = s; alphad[n] = d; }
}

// ---------------- edge passes, layer 1 (4 heads) ----------------
__global__ void k_edgea1(const int* __restrict__ src, const int* __restrict__ dst,
                         const float* __restrict__ ea, const float* __restrict__ cst, int itype,
                         const float* __restrict__ alphas, const float* __restrict__ alphad,
                         float* __restrict__ eval, float* __restrict__ den){
  int e = blockIdx.x*blockDim.x + threadIdx.x;
  if (e >= cE + cN) return;
  int s, d; float a0,a1,a2,a3;
  if (e < cE){
    s = src[e]; d = dst[e];
    float g = cst[K_GATES+itype];
    const float4* eap = (const float4*)(ea + (size_t)e*8);
    float4 u = eap[0], v = eap[1];
    float evv[8] = {u.x,u.y,u.z,u.w,v.x,v.y,v.z,v.w};
    a0=a1=a2=a3=0.f;
    #pragma unroll
    for (int k=0;k<8;k++){
      float4 w = *(const float4*)&cst[K_VE1 + (itype*8+k)*4];
      a0 += evv[k]*w.x; a1 += evv[k]*w.y; a2 += evv[k]*w.z; a3 += evv[k]*w.w;
    }
    a0*=g; a1*=g; a2*=g; a3*=g;
  } else {
    s = d = e - cE;
    a0 = cst[K_LOOP1+itype*4+0]; a1 = cst[K_LOOP1+itype*4+1];
    a2 = cst[K_LOOP1+itype*4+2]; a3 = cst[K_LOOP1+itype*4+3];
  }
  float4 as4 = *(const float4*)&alphas[s*4];
  float4 ad4 = *(const float4*)&alphad[d*4];
  float al[4] = {as4.x+ad4.x+a0, as4.y+ad4.y+a1, as4.z+ad4.z+a2, as4.w+ad4.w+a3};
  float ev[4];
  #pragma unroll
  for (int hh=0; hh<4; hh++){
    float a = al[hh]; a = a>0.f ? a : 0.2f*a;   // leaky_relu 0.2
    ev[hh] = expf(a);
    atomicAdd(&den[d*4+hh], ev[hh]);
  }
  *(float4*)&eval[(size_t)e*4] = make_float4(ev[0],ev[1],ev[2],ev[3]);
}

__global__ __launch_bounds__(256) void k_edgeb1(const int* __restrict__ src, const int* __restrict__ dst,
                        const float* __restrict__ eval, const float* __restrict__ h,
                        float* __restrict__ outn){
  int e = blockIdx.x*4 + (threadIdx.x>>6);
  if (e >= cE+cN) return;
  int lane = threadIdx.x & 63;
  int s, d;
  if (e < cE){ s = src[e]; d = dst[e]; } else { s = d = e - cE; }
  float4 ev = *(const float4*)&eval[(size_t)e*4];
  float e_lo = (lane & 32) ? ev.y : ev.x;    // head of channel lane
  float e_hi = (lane & 32) ? ev.w : ev.z;    // head of channel lane+64
  float hv0 = h[(size_t)s*128 + lane];
  float hv1 = h[(size_t)s*128 + 64 + lane];
  atomicAdd(&outn[(size_t)d*128 + lane],      hv0*e_lo);
  atomicAdd(&outn[(size_t)d*128 + 64 + lane], hv1*e_hi);
}

__global__ void k_epi1(float* __restrict__ outn, const float* __restrict__ den,
                       const float* __restrict__ b1){
  size_t idx = (size_t)blockIdx.x*blockDim.x + threadIdx.x;
  if (idx >= (size_t)cN*128) return;
  int n = (int)(idx >> 7), c = (int)(idx & 127);
  float v = outn[idx]/(den[n*4 + (c>>5)] + 1e-16f) + b1[c];
  outn[idx] = v > 0.f ? v : expm1f(v);       // ELU
}

// ---------------- edge passes, layer 2 (1 head) ----------------
__global__ void k_edgea2(const int* __restrict__ src, const int* __restrict__ dst,
                         const float* __restrict__ ea, const float* __restrict__ cst, int itype,
                         const float* __restrict__ alphas, const float* __restrict__ alphad,
                         float* __restrict__ eval, float* __restrict__ den){
  int e = blockIdx.x*blockDim.x + threadIdx.x;
  if (e >= cE + cN) return;
  int s, d; float ae;
  if (e < cE){
    s = src[e]; d = dst[e];
    float g = cst[K_GATES+itype];
    const float4* eap = (const float4*)(ea + (size_t)e*8);
    float4 u = eap[0], v = eap[1];
    float evv[8] = {u.x,u.y,u.z,u.w,v.x,v.y,v.z,v.w};
    float sdot = 0.f;
    #pragma unroll
    for (int k=0;k<8;k++) sdot += evv[k]*cst[K_VE2 + itype*8 + k];
    ae = g*sdot;
  } else { s = d = e - cE; ae = cst[K_LOOP2+itype]; }
  float a = alphas[s] + alphad[d] + ae;
  a = a>0.f ? a : 0.2f*a;
  float x = expf(a);
  atomicAdd(&den[d], x);
  eval[e] = x;
}

__global__ __launch_bounds__(256) void k_edgeb2(const int* __restrict__ src, const int* __restrict__ dst,
                        const float* __restrict__ eval, const float* __restrict__ h,
                        float* __restrict__ outn){
  int e = blockIdx.x*4 + (threadIdx.x>>6);
  if (e >= cE+cN) return;
  int lane = threadIdx.x & 63;
  int s, d;
  if (e < cE){ s = src[e]; d = dst[e]; } else { s = d = e - cE; }
  float ev = eval[e];
  atomicAdd(&outn[(size_t)d*128 + lane],      h[(size_t)s*128 + lane]*ev);
  atomicAdd(&outn[(size_t)d*128 + 64 + lane], h[(size_t)s*128 + 64 + lane]*ev);
}

__global__ void k_epi2(const float* __restrict__ outn, const float* __restrict__ den,
                       const float* __restrict__ b2, const float* __restrict__ cst, int itype,
                       float* __restrict__ acc){
  size_t idx = (size_t)blockIdx.x*blockDim.x + threadIdx.x;
  if (idx >= (size_t)cN*128) return;
  int n = (int)(idx >> 7), c = (int)(idx & 127);
  float w = cst[K_WTS+itype];
  float v = outn[idx]/(den[n] + 1e-16f) + b2[c];
  acc[idx] += w*v;
}

// ---------------- pooling + head MLP ----------------
__global__ void k_scores(const float* __restrict__ acc, const float* __restrict__ pw,
                         const float* __restrict__ pb, float* __restrict__ es){
  int v = blockIdx.x, l = threadIdx.x;
  const float* row = acc + (size_t)(cR+v)*128;
  float s = row[l]*pw[l] + row[64+l]*pw[64+l];
  for (int m=1;m<64;m<<=1) s += __shfl_xor(s,m,64);
  if (l==0) es[v] = expf(s + pb[0]);
}

__global__ void k_poolden(const int* __restrict__ mask, const float* __restrict__ es,
                          float* __restrict__ denp){
  int r = blockIdx.y;
  int hi = min(cV, (int)(blockIdx.x+1)*4096);
  float s = 0.f;
  for (int v = blockIdx.x*4096 + threadIdx.x; v < hi; v += 256)
    if (mask[(size_t)r*cV + v]) s += es[v];
  for (int m=1;m<64;m<<=1) s += __shfl_xor(s,m,64);
  __shared__ float wsm[4];
  if ((threadIdx.x&63)==0) wsm[threadIdx.x>>6] = s;
  __syncthreads();
  if (threadIdx.x==0) atomicAdd(&denp[r], wsm[0]+wsm[1]+wsm[2]+wsm[3]);
}

__global__ __launch_bounds__(128) void k_poolnum(const int* __restrict__ mask, const float* __restrict__ es,
                         const float* __restrict__ acc, float* __restrict__ pn){
  __shared__ float w[512];
  int r = blockIdx.y;
  int base = blockIdx.x*512;
  int lim = min(512, cV - base);
  for (int j = threadIdx.x; j < 512; j += 128){
    float wv = 0.f;
    if (j < lim && mask[(size_t)r*cV + base + j]) wv = es[base+j];
    w[j] = wv;
  }
  __syncthreads();
  int c = threadIdx.x;
  const float* veh = acc + (size_t)cR*128;
  float s = 0.f;
  for (int j=0;j<lim;j++){
    float wj = w[j];                    // uniform across wave -> cheap skip
    if (wj != 0.f) s += wj*veh[(size_t)(base+j)*128 + c];
  }
  atomicAdd(&pn[r*128+c], s);
}

__global__ __launch_bounds__(128) void k_mlp(const float* __restrict__ acc, const float* __restrict__ pn,
                     const float* __restrict__ denp,
                     const float* __restrict__ Wo1, const float* __restrict__ bo1,
                     const float* __restrict__ Wo2, const float* __restrict__ bo2,
                     const float* __restrict__ Wo3, const float* __restrict__ bo3,
                     float* __restrict__ dout){
  __shared__ float comb[256], q1[128], q2[64];
  int r = blockIdx.x, t = threadIdx.x;
  comb[t] = acc[(size_t)r*128 + t];
  float dp = denp[r];
  comb[128+t] = dp > 0.f ? pn[r*128+t]/dp : 0.f;
  __syncthreads();
  float s = bo1[t];
  for (int k=0;k<256;k++) s += comb[k]*Wo1[k*128+t];
  q1[t] = fmaxf(s, 0.f);
  __syncthreads();
  if (t < 64){
    float s2 = bo2[t];
    for (int k=0;k<128;k++) s2 += q1[k]*Wo2[k*64+t];
    q2[t] = fmaxf(s2, 0.f);
  }
  __syncthreads();
  if (t < 16){
    float s3 = bo3[t];
    for (int k=0;k<64;k++) s3 += q2[k]*Wo3[k*16+t];
    dout[r*16+t] = s3;
  }
}

// ---------------- launcher ----------------
extern "C" void kernel_launch(void* const* d_in, const int* in_sizes, int n_in,
                              void* d_out, int out_size, void* d_ws, size_t ws_size,
                              hipStream_t stream){
  const float* nf   = (const float*)d_in[0];
  const float* ea[3]= {(const float*)d_in[1],(const float*)d_in[2],(const float*)d_in[3]};
  const float* te   = (const float*)d_in[4];
  const float* etg  = (const float*)d_in[5];
  const float* eta  = (const float*)d_in[6];
  const float* W1   = (const float*)d_in[7];
  const float* as1  = (const float*)d_in[8];
  const float* ad1  = (const float*)d_in[9];
  const float* We1  = (const float*)d_in[10];
  const float* ae1  = (const float*)d_in[11];
  const float* b1   = (const float*)d_in[12];
  const float* W2   = (const float*)d_in[13];
  const float* as2  = (const float*)d_in[14];
  const float* ad2  = (const float*)d_in[15];
  const float* We2  = (const float*)d_in[16];
  const float* ae2  = (const float*)d_in[17];
  const float* b2   = (const float*)d_in[18];
  const float* pw   = (const float*)d_in[19];
  const float* pb   = (const float*)d_in[20];
  const float* Wo1  = (const float*)d_in[21];
  const float* bo1  = (const float*)d_in[22];
  const float* Wo2  = (const float*)d_in[23];
  const float* bo2  = (const float*)d_in[24];
  const float* Wo3  = (const float*)d_in[25];
  const float* bo3  = (const float*)d_in[26];
  const int*  nt    = (const int*)d_in[27];
  const int*  ei[3] = {(const int*)d_in[28],(const int*)d_in[29],(const int*)d_in[30]};
  const int*  cmask = (const int*)d_in[31];

  float* ws  = (float*)d_ws;
  float* out = (float*)d_out;

  float* cst = ws;
  float* x0  = ws + OFF_X0;
  float* h   = ws + OFF_H;
  float* outn= ws + OFF_OUT;
  float* acc = ws + OFF_ACC;
  float* ev  = ws + OFF_EV;
  float* den = ws + OFF_DEN;
  float* as_ = ws + OFF_AS;
  float* ad_ = ws + OFF_AD;
  float* es  = ws + OFF_ES;
  float* pn  = ws + OFF_PN;
  float* denp= ws + OFF_DENP;

  hipMemsetAsync(cst, 0, 1024*sizeof(float), stream);
  hipMemsetAsync(acc, 0, (size_t)cN*128*sizeof(float), stream);
  hipMemsetAsync(pn,  0, ((size_t)cR*128 + cR)*sizeof(float), stream);

  k_setup<<<1,128,0,stream>>>(etg, eta, We1, ae1, We2, ae2, cst, out);
  k_eamean<<<dim3(64,3),256,0,stream>>>(ea[0],ea[1],ea[2],cst);
  k_loopconsts<<<1,16,0,stream>>>(cst);
  k_x0<<<cN,64,0,stream>>>(nf, te, nt, x0);

  const int egrid  = (cE+cN+255)/256;
  const int ebgrid = (cE+cN+3)/4;

  for (int i=0;i<3;i++){
    const int* src = ei[i];
    const int* dst = ei[i] + cE;
    // ---- layer 1 ----
    k_gemm<41,44><<<dim3((cN+63)/64,2),256,0,stream>>>(x0, W1 + (size_t)i*41*128, h, cN);
    k_anode1<<<cN,64,0,stream>>>(h, as1 + i*128, ad1 + i*128, as_, ad_);
    hipMemsetAsync(den, 0, (size_t)cN*4*sizeof(float), stream);
    k_edgea1<<<egrid,256,0,stream>>>(src,dst,ea[i],cst,i,as_,ad_,ev,den);
    hipMemsetAsync(outn, 0, (size_t)cN*128*sizeof(float), stream);
    k_edgeb1<<<ebgrid,256,0,stream>>>(src,dst,ev,h,outn);
    k_epi1<<<(cN*128)/256,256,0,stream>>>(outn, den, b1 + i*128);
    // ---- layer 2 ----
    k_gemm<128,128><<<dim3((cN+63)/64,2),256,0,stream>>>(outn, W2 + (size_t)i*128*128, h, cN);
    k_anode2<<<cN,64,0,stream>>>(h, as2 + i*128, ad2 + i*128, as_, ad_);
    hipMemsetAsync(den, 0, (size_t)cN*sizeof(float), stream);
    k_edgea2<<<egrid,256,0,stream>>>(src,dst,ea[i],cst,i,as_,ad_,ev,den);
    hipMemsetAsync(outn, 0, (size_t)cN*128*sizeof(float), stream);
    k_edgeb2<<<ebgrid,256,0,stream>>>(src,dst,ev,h,outn);
    k_epi2<<<(cN*128)/256,256,0,stream>>>(outn, den, b2 + i*128, cst, i, acc);
  }

  k_scores<<<cV,64,0,stream>>>(acc, pw, pb, es);
  k_poolden<<<dim3((cV+4095)/4096,cR),256,0,stream>>>(cmask, es, denp);
  k_poolnum<<<dim3((cV+511)/512,cR),128,0,stream>>>(cmask, es, acc, pn);
  k_mlp<<<cR,128,0,stream>>>(acc, pn, denp, Wo1, bo1, Wo2, bo2, Wo3, bo3, out);
}

// Round 2
// 1799.615 us; speedup vs baseline: 1.6839x; 1.6839x over previous
//
#include <hip/hip_runtime.h>
#include <math.h>

// ---------------- problem constants ----------------
constexpr int cN  = 50000;
constexpr int cE  = 600000;
constexpr int cR  = 64;
constexpr int cV  = cN - cR;     // 49936
constexpr int cNF = 9;
constexpr int cIN = 41;          // 9 + 32

// ---------------- ws layout (4-byte units) ----------------
constexpr int K_GATES = 0;    // 3
constexpr int K_WTS   = 3;    // 3
constexpr int K_LOOP1 = 6;    // 3*4
constexpr int K_LOOP2 = 18;   // 3
constexpr int K_VE1   = 32;   // 3*8*4
constexpr int K_VE2   = 128;  // 3*8
constexpr int K_EASUM = 160;  // 3*8

constexpr size_t OFF_X0    = 1024;
constexpr size_t OFF_H     = OFF_X0  + (size_t)cN*cIN;     // 2051024
constexpr size_t OFF_OUT   = OFF_H   + (size_t)cN*128;     // h1(post-ELU) / gemm input
constexpr size_t OFF_ACC   = OFF_OUT + (size_t)cN*128;
constexpr size_t OFF_AS    = OFF_ACC + (size_t)cN*128;     // alpha_src (4/node L1, 1/node L2)
constexpr size_t OFF_AD    = OFF_AS  + (size_t)cN*4;
constexpr size_t OFF_ES    = OFF_AD  + (size_t)cN*4;
constexpr size_t OFF_PN    = OFF_ES  + (size_t)cN;
constexpr size_t OFF_DENP  = OFF_PN  + (size_t)cR*128;
constexpr size_t OFF_ROWOFF= OFF_DENP+ 64;                  // int, cN+1
constexpr size_t OFF_DEG   = OFF_ROWOFF + 50016;            // int, cN   (rounded)
constexpr size_t OFF_CNT   = OFF_DEG + (size_t)cN;          // int, cN (contiguous w/ DEG)
constexpr size_t OFF_SRCS  = OFF_CNT + (size_t)cN;          // int, cE
constexpr size_t OFF_EIDX  = OFF_SRCS+ (size_t)cE;          // int, cE
// end ~ 23.06M * 4B = 92.2 MB

// ---------------- small setup kernels ----------------
__global__ void k_setup(const float* __restrict__ etg, const float* __restrict__ eta,
                        const float* __restrict__ We1, const float* __restrict__ ae1,
                        const float* __restrict__ We2, const float* __restrict__ ae2,
                        float* __restrict__ cst, float* __restrict__ dout){
  int t = threadIdx.x; // 128 threads
  if (t < 3){
    cst[K_GATES+t] = 1.f/(1.f+expf(-etg[t]));
    float m = fmaxf(fmaxf(eta[0],eta[1]),eta[2]);
    float e0=expf(eta[0]-m), e1=expf(eta[1]-m), e2=expf(eta[2]-m);
    cst[K_WTS+t] = expf(eta[t]-m)/(e0+e1+e2);
    dout[1024+t] = eta[t];       // second tuple output
  }
  if (t < 96){ // ve1[(i*8+k)*4+h] = sum_c We1[i,k,h*32+c]*ae1[i,h,c]
    int i = t >> 5, k = (t>>2)&7, h = t&3;
    const float* w = We1 + ((size_t)(i*8+k))*128 + h*32;
    const float* a = ae1 + (i*4+h)*32;
    float s = 0.f;
    for (int c=0;c<32;c++) s += w[c]*a[c];
    cst[K_VE1 + t] = s;
  }
  if (t < 24){ // ve2[i*8+k] = sum_c We2[i,k,c]*ae2[i,c]
    int i = t >> 3, k = t & 7;
    const float* w = We2 + ((size_t)(i*8+k))*128;
    const float* a = ae2 + i*128;
    float s = 0.f;
    for (int c=0;c<128;c++) s += w[c]*a[c];
    cst[K_VE2 + t] = s;
  }
}

__global__ void k_eamean(const float* __restrict__ ea0, const float* __restrict__ ea1,
                         const float* __restrict__ ea2, float* __restrict__ cst){
  int i = blockIdx.y;
  const float* ea = (i==0)?ea0:(i==1)?ea1:ea2;
  float s[8];
  #pragma unroll
  for (int k=0;k<8;k++) s[k]=0.f;
  for (int e = blockIdx.x*blockDim.x + threadIdx.x; e < cE; e += gridDim.x*blockDim.x){
    const float4* p = (const float4*)(ea + (size_t)e*8);
    float4 a = p[0], b = p[1];
    s[0]+=a.x; s[1]+=a.y; s[2]+=a.z; s[3]+=a.w;
    s[4]+=b.x; s[5]+=b.y; s[6]+=b.z; s[7]+=b.w;
  }
  for (int m=1;m<64;m<<=1){
    #pragma unroll
    for (int k=0;k<8;k++) s[k] += __shfl_xor(s[k], m, 64);
  }
  if ((threadIdx.x & 63) == 0){
    #pragma unroll
    for (int k=0;k<8;k++) atomicAdd(&cst[K_EASUM + i*8 + k], s[k]);
  }
}

__global__ void k_loopconsts(float* __restrict__ cst){
  int t = threadIdx.x;
  if (t < 12){
    int i=t>>2, h=t&3;
    float s=0.f;
    for (int k=0;k<8;k++) s += (cst[K_EASUM+i*8+k]/(float)cE)*cst[K_VE1+(i*8+k)*4+h];
    cst[K_LOOP1+t] = cst[K_GATES+i]*s;
  } else if (t < 15){
    int i=t-12; float s=0.f;
    for (int k=0;k<8;k++) s += (cst[K_EASUM+i*8+k]/(float)cE)*cst[K_VE2+i*8+k];
    cst[K_LOOP2+i] = cst[K_GATES+i]*s;
  }
}

__global__ void k_x0(const float* __restrict__ nf, const float* __restrict__ te,
                     const int* __restrict__ nt, float* __restrict__ x0){
  int n = blockIdx.x, j = threadIdx.x;
  if (j >= cIN) return;
  float v = (j < cNF) ? nf[(size_t)n*cNF + j] : te[nt[n]*32 + (j-cNF)];
  x0[(size_t)n*cIN + j] = v;
}

// ---------------- CSR build ----------------
__global__ void k_deg(const int* __restrict__ dst, int* __restrict__ deg){
  int e = blockIdx.x*256 + threadIdx.x;
  if (e < cE) atomicAdd(&deg[dst[e]], 1);
}

__global__ __launch_bounds__(1024) void k_scan(const int* __restrict__ deg, int* __restrict__ rowoff){
  __shared__ int tile[1024];
  __shared__ int carry_s;
  if (threadIdx.x==0) carry_s = 0;
  __syncthreads();
  for (int base=0; base<cN; base+=1024){
    int i = base + threadIdx.x;
    int v = (i<cN)? deg[i] : 0;
    tile[threadIdx.x] = v;
    __syncthreads();
    for (int off=1; off<1024; off<<=1){
      int t = (threadIdx.x>=off) ? tile[threadIdx.x-off] : 0;
      __syncthreads();
      tile[threadIdx.x] += t;
      __syncthreads();
    }
    int carry = carry_s;
    if (i<cN) rowoff[i] = carry + tile[threadIdx.x] - v;
    __syncthreads();
    if (threadIdx.x==1023){
      carry_s = carry + tile[1023];
      if (base+1024 >= cN) rowoff[cN] = carry + tile[1023];
    }
    __syncthreads();
  }
}

__global__ void k_scatter(const int* __restrict__ src, const int* __restrict__ dst,
                          const int* __restrict__ rowoff, int* __restrict__ cnt,
                          int* __restrict__ srcs, int* __restrict__ eidx){
  int e = blockIdx.x*256 + threadIdx.x;
  if (e >= cE) return;
  int d = dst[e];
  int p = rowoff[d] + atomicAdd(&cnt[d], 1);
  srcs[p] = src[e];
  eidx[p] = e;
}

// ---------------- GEMM ----------------
template<int K, int KS>
__global__ __launch_bounds__(256) void k_gemm(const float* __restrict__ A,
                                              const float* __restrict__ B,
                                              float* __restrict__ C, int nrows){
  __shared__ float sA[64][KS];
  __shared__ float sB[K][64];
  const int tid = threadIdx.x;
  const int nb = blockIdx.x * 64;
  const int ch = blockIdx.y;
  for (int idx = tid; idx < 64*K; idx += 256){
    int n = idx / K, k = idx - n*K;
    int row = nb + n; if (row >= nrows) row = nrows - 1;
    sA[n][k] = A[(size_t)row*K + k];
  }
  for (int idx = tid; idx < K*64; idx += 256){
    int k = idx >> 6, c = idx & 63;
    sB[k][c] = B[k*128 + ch*64 + c];
  }
  __syncthreads();
  const int cg = tid & 15, ng = tid >> 4;
  const int c0 = cg*4, n0 = ng*4;
  float acc[4][4] = {};
  int k = 0;
  for (; k + 4 <= K; k += 4){
    float4 a4[4], w4[4];
    #pragma unroll
    for (int ii=0; ii<4; ii++) a4[ii] = *(const float4*)&sA[n0+ii][k];
    #pragma unroll
    for (int kk=0; kk<4; kk++) w4[kk] = *(const float4*)&sB[k+kk][c0];
    const float* ap = (const float*)a4;
    const float* wp = (const float*)w4;
    #pragma unroll
    for (int ii=0; ii<4; ii++)
      #pragma unroll
      for (int kk=0; kk<4; kk++)
        #pragma unroll
        for (int jj=0; jj<4; jj++)
          acc[ii][jj] += ap[ii*4+kk]*wp[kk*4+jj];
  }
  for (; k < K; k++){
    float4 wv = *(const float4*)&sB[k][c0];
    #pragma unroll
    for (int ii=0; ii<4; ii++){
      float a = sA[n0+ii][k];
      acc[ii][0]+=a*wv.x; acc[ii][1]+=a*wv.y; acc[ii][2]+=a*wv.z; acc[ii][3]+=a*wv.w;
    }
  }
  #pragma unroll
  for (int ii=0; ii<4; ii++){
    int row = nb + n0 + ii;
    if (row < nrows){
      float4 v = make_float4(acc[ii][0],acc[ii][1],acc[ii][2],acc[ii][3]);
      *(float4*)&C[(size_t)row*128 + ch*64 + c0] = v;
    }
  }
}

// ---------------- per-node attention logit pieces ----------------
__global__ void k_anode1(const float* __restrict__ h, const float* __restrict__ as_,
                         const float* __restrict__ ad_, float* __restrict__ alphas,
                         float* __restrict__ alphad){
  int n = blockIdx.x, l = threadIdx.x; // 64 threads
  float h0 = h[(size_t)n*128 + l], h1 = h[(size_t)n*128 + 64 + l];
  float s0 = h0*as_[l], s1 = h1*as_[64+l];
  float d0 = h0*ad_[l], d1 = h1*ad_[64+l];
  for (int m=1;m<32;m<<=1){
    s0 += __shfl_xor(s0,m,64); s1 += __shfl_xor(s1,m,64);
    d0 += __shfl_xor(d0,m,64); d1 += __shfl_xor(d1,m,64);
  }
  if ((l&31)==0){
    int hh = l>>5;
    alphas[n*4+hh]   = s0; alphas[n*4+2+hh] = s1;
    alphad[n*4+hh]   = d0; alphad[n*4+2+hh] = d1;
  }
}

__global__ void k_anode2(const float* __restrict__ h, const float* __restrict__ as_,
                         const float* __restrict__ ad_, float* __restrict__ alphas,
                         float* __restrict__ alphad){
  int n = blockIdx.x, l = threadIdx.x;
  float h0 = h[(size_t)n*128+l], h1 = h[(size_t)n*128+64+l];
  float s = h0*as_[l] + h1*as_[64+l];
  float d = h0*ad_[l] + h1*ad_[64+l];
  for (int m=1;m<64;m<<=1){ s += __shfl_xor(s,m,64); d += __shfl_xor(d,m,64); }
  if (l==0){ alphas[n] = s; alphad[n] = d; }
}

// ---------------- fused CSR aggregation, layer 1 (4 heads) ----------------
// one wave per dst node; lane l owns channels l and l+64.
__global__ __launch_bounds__(256) void k_agg1(
    const int* __restrict__ rowoff, const int* __restrict__ srcs, const int* __restrict__ eidx,
    const float* __restrict__ ea, const float* __restrict__ cst, int itype,
    const float* __restrict__ alphas, const float* __restrict__ alphad,
    const float* __restrict__ h, const float* __restrict__ b1, float* __restrict__ outn)
{
  int n = blockIdx.x*4 + (threadIdx.x>>6);
  if (n >= cN) return;
  int l = threadIdx.x & 63;
  int hlo = l>>5;          // head of channel l     (0 or 1)
  int hhi = 2 + hlo;       // head of channel l+64  (2 or 3)
  float g = cst[K_GATES+itype];
  float ve_lo[8], ve_hi[8];
  #pragma unroll
  for (int k=0;k<8;k++){
    ve_lo[k] = cst[K_VE1+(itype*8+k)*4+hlo];
    ve_hi[k] = cst[K_VE1+(itype*8+k)*4+hhi];
  }
  float ad_lo = alphad[n*4+hlo], ad_hi = alphad[n*4+hhi];
  // self-loop contribution
  float a_lo = alphas[n*4+hlo] + ad_lo + cst[K_LOOP1+itype*4+hlo];
  float a_hi = alphas[n*4+hhi] + ad_hi + cst[K_LOOP1+itype*4+hhi];
  a_lo = a_lo>0.f?a_lo:0.2f*a_lo; a_hi = a_hi>0.f?a_hi:0.2f*a_hi;
  float e_lo = expf(a_lo), e_hi = expf(a_hi);
  float den_lo = e_lo, den_hi = e_hi;
  float acc_lo = e_lo * h[(size_t)n*128 + l];
  float acc_hi = e_hi * h[(size_t)n*128 + 64 + l];
  int start = rowoff[n], end = rowoff[n+1];
  for (int cb = start; cb < end; cb += 64){
    int m = min(64, end-cb);
    int md_s = 0, md_e = 0;
    if (l < m){ md_s = srcs[cb+l]; md_e = eidx[cb+l]; }
    for (int t=0;t<m;t++){
      int s  = __shfl(md_s, t, 64);
      int ei = __shfl(md_e, t, 64);
      const float4* eap = (const float4*)(ea + (size_t)ei*8);
      float4 u = eap[0], v = eap[1];
      float ew[8] = {u.x,u.y,u.z,u.w,v.x,v.y,v.z,v.w};
      float ae_lo=0.f, ae_hi=0.f;
      #pragma unroll
      for (int k=0;k<8;k++){ ae_lo += ew[k]*ve_lo[k]; ae_hi += ew[k]*ve_hi[k]; }
      float al = alphas[s*4+hlo] + ad_lo + g*ae_lo;
      float ah = alphas[s*4+hhi] + ad_hi + g*ae_hi;
      al = al>0.f?al:0.2f*al; ah = ah>0.f?ah:0.2f*ah;
      float elo = expf(al), ehi = expf(ah);
      den_lo += elo; den_hi += ehi;
      acc_lo += elo * h[(size_t)s*128 + l];
      acc_hi += ehi * h[(size_t)s*128 + 64 + l];
    }
  }
  float vlo = acc_lo/(den_lo+1e-16f) + b1[l];
  float vhi = acc_hi/(den_hi+1e-16f) + b1[64+l];
  outn[(size_t)n*128+l]    = vlo>0.f?vlo:expm1f(vlo);   // ELU
  outn[(size_t)n*128+64+l] = vhi>0.f?vhi:expm1f(vhi);
}

// ---------------- fused CSR aggregation, layer 2 (1 head) ----------------
__global__ __launch_bounds__(256) void k_agg2(
    const int* __restrict__ rowoff, const int* __restrict__ srcs, const int* __restrict__ eidx,
    const float* __restrict__ ea, const float* __restrict__ cst, int itype,
    const float* __restrict__ alphas, const float* __restrict__ alphad,
    const float* __restrict__ h, const float* __restrict__ b2, float* __restrict__ acc_out)
{
  int n = blockIdx.x*4 + (threadIdx.x>>6);
  if (n >= cN) return;
  int l = threadIdx.x & 63;
  float g = cst[K_GATES+itype];
  float ve[8];
  #pragma unroll
  for (int k=0;k<8;k++) ve[k] = cst[K_VE2+itype*8+k];
  float ad = alphad[n];
  float a = alphas[n] + ad + cst[K_LOOP2+itype];
  a = a>0.f?a:0.2f*a;
  float e = expf(a);
  float den = e;
  float acc_lo = e * h[(size_t)n*128 + l];
  float acc_hi = e * h[(size_t)n*128 + 64 + l];
  int start = rowoff[n], end = rowoff[n+1];
  for (int cb = start; cb < end; cb += 64){
    int m = min(64, end-cb);
    int md_s = 0, md_e = 0;
    if (l < m){ md_s = srcs[cb+l]; md_e = eidx[cb+l]; }
    for (int t=0;t<m;t++){
      int s  = __shfl(md_s, t, 64);
      int ei = __shfl(md_e, t, 64);
      const float4* eap = (const float4*)(ea + (size_t)ei*8);
      float4 u = eap[0], v = eap[1];
      float ae = u.x*ve[0]+u.y*ve[1]+u.z*ve[2]+u.w*ve[3]
               + v.x*ve[4]+v.y*ve[5]+v.z*ve[6]+v.w*ve[7];
      float al = alphas[s] + ad + g*ae;
      al = al>0.f?al:0.2f*al;
      float el = expf(al);
      den += el;
      acc_lo += el * h[(size_t)s*128 + l];
      acc_hi += el * h[(size_t)s*128 + 64 + l];
    }
  }
  float w = cst[K_WTS+itype];
  size_t o = (size_t)n*128 + l;
  acc_out[o]    += w*(acc_lo/(den+1e-16f) + b2[l]);
  acc_out[o+64] += w*(acc_hi/(den+1e-16f) + b2[64+l]);
}

// ---------------- pooling + head MLP ----------------
__global__ void k_scores(const float* __restrict__ acc, const float* __restrict__ pw,
                         const float* __restrict__ pb, float* __restrict__ es){
  int v = blockIdx.x, l = threadIdx.x;
  const float* row = acc + (size_t)(cR+v)*128;
  float s = row[l]*pw[l] + row[64+l]*pw[64+l];
  for (int m=1;m<64;m<<=1) s += __shfl_xor(s,m,64);
  if (l==0) es[v] = expf(s + pb[0]);
}

__global__ void k_poolden(const int* __restrict__ mask, const float* __restrict__ es,
                          float* __restrict__ denp){
  int r = blockIdx.y;
  int hi = min(cV, (int)(blockIdx.x+1)*4096);
  float s = 0.f;
  for (int v = blockIdx.x*4096 + threadIdx.x; v < hi; v += 256)
    if (mask[(size_t)r*cV + v]) s += es[v];
  for (int m=1;m<64;m<<=1) s += __shfl_xor(s,m,64);
  __shared__ float wsm[4];
  if ((threadIdx.x&63)==0) wsm[threadIdx.x>>6] = s;
  __syncthreads();
  if (threadIdx.x==0) atomicAdd(&denp[r], wsm[0]+wsm[1]+wsm[2]+wsm[3]);
}

__global__ __launch_bounds__(128) void k_poolnum(const int* __restrict__ mask, const float* __restrict__ es,
                         const float* __restrict__ acc, float* __restrict__ pn){
  __shared__ float w[512];
  int r = blockIdx.y;
  int base = blockIdx.x*512;
  int lim = min(512, cV - base);
  for (int j = threadIdx.x; j < 512; j += 128){
    float wv = 0.f;
    if (j < lim && mask[(size_t)r*cV + base + j]) wv = es[base+j];
    w[j] = wv;
  }
  __syncthreads();
  int c = threadIdx.x;
  const float* veh = acc + (size_t)cR*128;
  float s = 0.f;
  for (int j=0;j<lim;j++){
    float wj = w[j];
    if (wj != 0.f) s += wj*veh[(size_t)(base+j)*128 + c];
  }
  atomicAdd(&pn[r*128+c], s);
}

__global__ __launch_bounds__(128) void k_mlp(const float* __restrict__ acc, const float* __restrict__ pn,
                     const float* __restrict__ denp,
                     const float* __restrict__ Wo1, const float* __restrict__ bo1,
                     const float* __restrict__ Wo2, const float* __restrict__ bo2,
                     const float* __restrict__ Wo3, const float* __restrict__ bo3,
                     float* __restrict__ dout){
  __shared__ float comb[256], q1[128], q2[64];
  int r = blockIdx.x, t = threadIdx.x;
  comb[t] = acc[(size_t)r*128 + t];
  float dp = denp[r];
  comb[128+t] = dp > 0.f ? pn[r*128+t]/dp : 0.f;
  __syncthreads();
  float s = bo1[t];
  for (int k=0;k<256;k++) s += comb[k]*Wo1[k*128+t];
  q1[t] = fmaxf(s, 0.f);
  __syncthreads();
  if (t < 64){
    float s2 = bo2[t];
    for (int k=0;k<128;k++) s2 += q1[k]*Wo2[k*64+t];
    q2[t] = fmaxf(s2, 0.f);
  }
  __syncthreads();
  if (t < 16){
    float s3 = bo3[t];
    for (int k=0;k<64;k++) s3 += q2[k]*Wo3[k*16+t];
    dout[r*16+t] = s3;
  }
}

// ---------------- launcher ----------------
extern "C" void kernel_launch(void* const* d_in, const int* in_sizes, int n_in,
                              void* d_out, int out_size, void* d_ws, size_t ws_size,
                              hipStream_t stream){
  const float* nf   = (const float*)d_in[0];
  const float* ea[3]= {(const float*)d_in[1],(const float*)d_in[2],(const float*)d_in[3]};
  const float* te   = (const float*)d_in[4];
  const float* etg  = (const float*)d_in[5];
  const float* eta  = (const float*)d_in[6];
  const float* W1   = (const float*)d_in[7];
  const float* as1  = (const float*)d_in[8];
  const float* ad1  = (const float*)d_in[9];
  const float* We1  = (const float*)d_in[10];
  const float* ae1  = (const float*)d_in[11];
  const float* b1   = (const float*)d_in[12];
  const float* W2   = (const float*)d_in[13];
  const float* as2  = (const float*)d_in[14];
  const float* ad2  = (const float*)d_in[15];
  const float* We2  = (const float*)d_in[16];
  const float* ae2  = (const float*)d_in[17];
  const float* b2   = (const float*)d_in[18];
  const float* pw   = (const float*)d_in[19];
  const float* pb   = (const float*)d_in[20];
  const float* Wo1  = (const float*)d_in[21];
  const float* bo1  = (const float*)d_in[22];
  const float* Wo2  = (const float*)d_in[23];
  const float* bo2  = (const float*)d_in[24];
  const float* Wo3  = (const float*)d_in[25];
  const float* bo3  = (const float*)d_in[26];
  const int*  nt    = (const int*)d_in[27];
  const int*  ei[3] = {(const int*)d_in[28],(const int*)d_in[29],(const int*)d_in[30]};
  const int*  cmask = (const int*)d_in[31];

  float* ws  = (float*)d_ws;
  float* out = (float*)d_out;

  float* cst  = ws;
  float* x0   = ws + OFF_X0;
  float* h    = ws + OFF_H;
  float* outn = ws + OFF_OUT;
  float* acc  = ws + OFF_ACC;
  float* as_  = ws + OFF_AS;
  float* ad_  = ws + OFF_AD;
  float* es   = ws + OFF_ES;
  float* pn   = ws + OFF_PN;
  float* denp = ws + OFF_DENP;
  int* rowoff = (int*)(ws + OFF_ROWOFF);
  int* deg    = (int*)(ws + OFF_DEG);
  int* cnt    = (int*)(ws + OFF_CNT);
  int* srcs   = (int*)(ws + OFF_SRCS);
  int* eidx   = (int*)(ws + OFF_EIDX);

  hipMemsetAsync(cst, 0, 1024*sizeof(float), stream);
  hipMemsetAsync(acc, 0, (size_t)cN*128*sizeof(float), stream);
  hipMemsetAsync(pn,  0, ((size_t)cR*128 + cR)*sizeof(float), stream);

  k_setup<<<1,128,0,stream>>>(etg, eta, We1, ae1, We2, ae2, cst, out);
  k_eamean<<<dim3(64,3),256,0,stream>>>(ea[0],ea[1],ea[2],cst);
  k_loopconsts<<<1,16,0,stream>>>(cst);
  k_x0<<<cN,64,0,stream>>>(nf, te, nt, x0);

  const int egrid  = (cE+255)/256;
  const int ngrid  = (cN+3)/4;

  for (int i=0;i<3;i++){
    const int* src = ei[i];
    const int* dst = ei[i] + cE;
    // ---- CSR build (shared by both layers of this type) ----
    hipMemsetAsync(deg, 0, (size_t)2*cN*sizeof(int), stream);   // deg + cnt contiguous
    k_deg<<<egrid,256,0,stream>>>(dst, deg);
    k_scan<<<1,1024,0,stream>>>(deg, rowoff);
    k_scatter<<<egrid,256,0,stream>>>(src, dst, rowoff, cnt, srcs, eidx);
    // ---- layer 1 ----
    k_gemm<41,44><<<dim3((cN+63)/64,2),256,0,stream>>>(x0, W1 + (size_t)i*41*128, h, cN);
    k_anode1<<<cN,64,0,stream>>>(h, as1 + i*128, ad1 + i*128, as_, ad_);
    k_agg1<<<ngrid,256,0,stream>>>(rowoff, srcs, eidx, ea[i], cst, i, as_, ad_, h, b1 + i*128, outn);
    // ---- layer 2 ----
    k_gemm<128,128><<<dim3((cN+63)/64,2),256,0,stream>>>(outn, W2 + (size_t)i*128*128, h, cN);
    k_anode2<<<cN,64,0,stream>>>(h, as2 + i*128, ad2 + i*128, as_, ad_);
    k_agg2<<<ngrid,256,0,stream>>>(rowoff, srcs, eidx, ea[i], cst, i, as_, ad_, h, b2 + i*128, acc);
  }

  k_scores<<<cV,64,0,stream>>>(acc, pw, pb, es);
  k_poolden<<<dim3((cV+4095)/4096,cR),256,0,stream>>>(cmask, es, denp);
  k_poolnum<<<dim3((cV+511)/512,cR),128,0,stream>>>(cmask, es, acc, pn);
  k_mlp<<<cR,128,0,stream>>>(acc, pn, denp, Wo1, bo1, Wo2, bo2, Wo3, bo3, out);
}

// Round 5
// 1356.777 us; speedup vs baseline: 2.2336x; 1.3264x over previous
//
#include <hip/hip_runtime.h>
#include <math.h>

// ---------------- problem constants ----------------
constexpr int cN  = 50000;
constexpr int cE  = 600000;
constexpr int cR  = 64;
constexpr int cV  = cN - cR;     // 49936
constexpr int cNF = 9;
constexpr int cIN = 41;          // 9 + 32

// ---------------- const-region sub-offsets (floats) ----------------
constexpr int K_GATES = 0;    // 3
constexpr int K_WTS   = 3;    // 3
constexpr int K_LOOP1 = 6;    // 3*4
constexpr int K_LOOP2 = 18;   // 3
constexpr int K_VE1   = 32;   // 3*8*4
constexpr int K_VE2   = 128;  // 3*8
constexpr int K_EASUM = 160;  // 3*8

// ---------------- ws layout (float units) ----------------
constexpr size_t OFF_X0    = 1024;
constexpr size_t OFF_H     = OFF_X0  + 2050048;   // x0: 50000*41 = 2,050,000 (padded)
constexpr size_t OFF_OUT   = OFF_H   + 6400000;
constexpr size_t OFF_ACC   = OFF_OUT + 6400000;
constexpr size_t OFF_AS    = OFF_ACC + 6400000;   // 200,000
constexpr size_t OFF_AD    = OFF_AS  + 200000;    // 200,000
constexpr size_t OFF_ES    = OFF_AD  + 200000;    // 50,048
constexpr size_t OFF_PN    = OFF_ES  + 50048;     // 8192
constexpr size_t OFF_DENP  = OFF_PN  + 8192;      // 64
constexpr size_t OFF_ROWOFF= OFF_DENP+ 64;        // int cN+1 -> 50,016
constexpr size_t OFF_DEG   = OFF_ROWOFF + 50016;  // int cN
constexpr size_t OFF_CNT   = OFF_DEG + 50000;     // int cN (contiguous with DEG)
constexpr size_t OFF_SRCS  = OFF_CNT + 50000;     // int cE
constexpr size_t OFF_AE1   = OFF_SRCS+ 600000;    // float4 * cE  (16B aligned: offset%4==0)
constexpr size_t OFF_AE2   = OFF_AE1 + 2400000;   // float cE
constexpr size_t OFF_BSUM  = OFF_AE2 + 600000;    // int 64
constexpr size_t OFF_BOFF  = OFF_BSUM+ 64;        // int 64
// total ~25.46M floats = ~102 MB

// ---------------- small setup kernels ----------------
__global__ void k_setup(const float* __restrict__ etg, const float* __restrict__ eta,
                        const float* __restrict__ We1, const float* __restrict__ ae1,
                        const float* __restrict__ We2, const float* __restrict__ ae2,
                        float* __restrict__ cst, float* __restrict__ dout){
  int t = threadIdx.x; // 128 threads
  if (t < 3){
    cst[K_GATES+t] = 1.f/(1.f+expf(-etg[t]));
    float m = fmaxf(fmaxf(eta[0],eta[1]),eta[2]);
    float e0=expf(eta[0]-m), e1=expf(eta[1]-m), e2=expf(eta[2]-m);
    cst[K_WTS+t] = expf(eta[t]-m)/(e0+e1+e2);
    dout[1024+t] = eta[t];       // second tuple output
  }
  if (t < 96){ // ve1[(i*8+k)*4+h] = sum_c We1[i,k,h*32+c]*ae1[i,h,c]
    int i = t >> 5, k = (t>>2)&7, h = t&3;
    const float* w = We1 + ((size_t)(i*8+k))*128 + h*32;
    const float* a = ae1 + (i*4+h)*32;
    float s = 0.f;
    for (int c=0;c<32;c++) s += w[c]*a[c];
    cst[K_VE1 + t] = s;
  }
  if (t < 24){ // ve2[i*8+k] = sum_c We2[i,k,c]*ae2[i,c]
    int i = t >> 3, k = t & 7;
    const float* w = We2 + ((size_t)(i*8+k))*128;
    const float* a = ae2 + i*128;
    float s = 0.f;
    for (int c=0;c<128;c++) s += w[c]*a[c];
    cst[K_VE2 + t] = s;
  }
}

__global__ void k_eamean(const float* __restrict__ ea0, const float* __restrict__ ea1,
                         const float* __restrict__ ea2, float* __restrict__ cst){
  int i = blockIdx.y;
  const float* ea = (i==0)?ea0:(i==1)?ea1:ea2;
  float s[8];
  #pragma unroll
  for (int k=0;k<8;k++) s[k]=0.f;
  for (int e = blockIdx.x*blockDim.x + threadIdx.x; e < cE; e += gridDim.x*blockDim.x){
    const float4* p = (const float4*)(ea + (size_t)e*8);
    float4 a = p[0], b = p[1];
    s[0]+=a.x; s[1]+=a.y; s[2]+=a.z; s[3]+=a.w;
    s[4]+=b.x; s[5]+=b.y; s[6]+=b.z; s[7]+=b.w;
  }
  for (int m=1;m<64;m<<=1){
    #pragma unroll
    for (int k=0;k<8;k++) s[k] += __shfl_xor(s[k], m, 64);
  }
  if ((threadIdx.x & 63) == 0){
    #pragma unroll
    for (int k=0;k<8;k++) atomicAdd(&cst[K_EASUM + i*8 + k], s[k]);
  }
}

__global__ void k_loopconsts(float* __restrict__ cst){
  int t = threadIdx.x;
  if (t < 12){
    int i=t>>2, h=t&3;
    float s=0.f;
    for (int k=0;k<8;k++) s += (cst[K_EASUM+i*8+k]/(float)cE)*cst[K_VE1+(i*8+k)*4+h];
    cst[K_LOOP1+t] = cst[K_GATES+i]*s;
  } else if (t < 15){
    int i=t-12; float s=0.f;
    for (int k=0;k<8;k++) s += (cst[K_EASUM+i*8+k]/(float)cE)*cst[K_VE2+i*8+k];
    cst[K_LOOP2+i] = cst[K_GATES+i]*s;
  }
}

__global__ void k_x0(const float* __restrict__ nf, const float* __restrict__ te,
                     const int* __restrict__ nt, float* __restrict__ x0){
  int n = blockIdx.x, j = threadIdx.x;
  if (j >= cIN) return;
  float v = (j < cNF) ? nf[(size_t)n*cNF + j] : te[nt[n]*32 + (j-cNF)];
  x0[(size_t)n*cIN + j] = v;
}

// ---------------- CSR build ----------------
__global__ void k_deg(const int* __restrict__ dst, int* __restrict__ deg){
  int e = blockIdx.x*256 + threadIdx.x;
  if (e < cE) atomicAdd(&deg[dst[e]], 1);
}

__global__ __launch_bounds__(1024) void k_bsum(const int* __restrict__ deg, int* __restrict__ bsum){
  int b=blockIdx.x, t=threadIdx.x, i=b*1024+t;
  int v=(i<cN)?deg[i]:0;
  for(int m=1;m<64;m<<=1) v += __shfl_xor(v,m,64);
  __shared__ int wsm[16];
  if((t&63)==0) wsm[t>>6]=v;
  __syncthreads();
  if(t==0){int s=0; for(int k=0;k<16;k++) s+=wsm[k]; bsum[b]=s;}
}

__global__ void k_bscan(const int* __restrict__ bsum, int* __restrict__ boff){
  int t = threadIdx.x;           // 64 threads, 49 tiles
  int v = (t<49)? bsum[t] : 0;
  int x = v;
  for (int off=1; off<64; off<<=1){
    int y = __shfl_up(x, off, 64);
    if (t>=off) x += y;
  }
  if (t<49) boff[t] = x - v;     // exclusive tile offsets
}

__global__ __launch_bounds__(1024) void k_tilescan(const int* __restrict__ deg,
                        const int* __restrict__ boff, int* __restrict__ rowoff){
  __shared__ int sa[1024], sb[1024];
  int b = blockIdx.x, t = threadIdx.x;
  int i = b*1024 + t;
  int v = (i<cN)? deg[i] : 0;
  sa[t] = v; __syncthreads();
  int* cur = sa; int* nxt = sb;
  for (int off=1; off<1024; off<<=1){
    int x = cur[t];
    if (t>=off) x += cur[t-off];
    nxt[t] = x;
    __syncthreads();
    int* tmp=cur; cur=nxt; nxt=tmp;
  }
  if (i<cN) rowoff[i] = boff[b] + cur[t] - v;   // exclusive
  if (i==cN-1) rowoff[cN] = cE;
}

// fused scatter: CSR placement + per-edge logit consts (ea read once, coalesced)
__global__ void k_scatter(const int* __restrict__ src, const int* __restrict__ dst,
                          const float* __restrict__ ea, const float* __restrict__ cst, int itype,
                          const int* __restrict__ rowoff, int* __restrict__ cnt,
                          int* __restrict__ srcs, float4* __restrict__ ae1p,
                          float* __restrict__ ae2p){
  int e = blockIdx.x*256 + threadIdx.x;
  if (e >= cE) return;
  int d = dst[e];
  int p = rowoff[d] + atomicAdd(&cnt[d], 1);
  srcs[p] = src[e];
  const float4* eap = (const float4*)(ea + (size_t)e*8);
  float4 u = eap[0], v = eap[1];
  float ew[8] = {u.x,u.y,u.z,u.w,v.x,v.y,v.z,v.w};
  float g = cst[K_GATES+itype];
  float a1x=0,a1y=0,a1z=0,a1w=0,a2=0;
  #pragma unroll
  for (int k=0;k<8;k++){
    float evk = ew[k];
    const float* vp = &cst[K_VE1+(itype*8+k)*4];
    a1x += evk*vp[0]; a1y += evk*vp[1]; a1z += evk*vp[2]; a1w += evk*vp[3];
    a2  += evk*cst[K_VE2+itype*8+k];
  }
  ae1p[p] = make_float4(g*a1x, g*a1y, g*a1z, g*a1w);
  ae2p[p] = g*a2;
}

// ---------------- GEMM ----------------
template<int K, int KS>
__global__ __launch_bounds__(256) void k_gemm(const float* __restrict__ A,
                                              const float* __restrict__ B,
                                              float* __restrict__ C, int nrows){
  __shared__ float sA[64][KS];
  __shared__ float sB[K][64];
  const int tid = threadIdx.x;
  const int nb = blockIdx.x * 64;
  const int ch = blockIdx.y;
  for (int idx = tid; idx < 64*K; idx += 256){
    int n = idx / K, k = idx - n*K;
    int row = nb + n; if (row >= nrows) row = nrows - 1;
    sA[n][k] = A[(size_t)row*K + k];
  }
  for (int idx = tid; idx < K*64; idx += 256){
    int k = idx >> 6, c = idx & 63;
    sB[k][c] = B[k*128 + ch*64 + c];
  }
  __syncthreads();
  const int cg = tid & 15, ng = tid >> 4;
  const int c0 = cg*4, n0 = ng*4;
  float acc[4][4] = {};
  int k = 0;
  for (; k + 4 <= K; k += 4){
    float4 a4[4], w4[4];
    #pragma unroll
    for (int ii=0; ii<4; ii++) a4[ii] = *(const float4*)&sA[n0+ii][k];
    #pragma unroll
    for (int kk=0; kk<4; kk++) w4[kk] = *(const float4*)&sB[k+kk][c0];
    const float* ap = (const float*)a4;
    const float* wp = (const float*)w4;
    #pragma unroll
    for (int ii=0; ii<4; ii++)
      #pragma unroll
      for (int kk=0; kk<4; kk++)
        #pragma unroll
        for (int jj=0; jj<4; jj++)
          acc[ii][jj] += ap[ii*4+kk]*wp[kk*4+jj];
  }
  for (; k < K; k++){
    float4 wv = *(const float4*)&sB[k][c0];
    #pragma unroll
    for (int ii=0; ii<4; ii++){
      float a = sA[n0+ii][k];
      acc[ii][0]+=a*wv.x; acc[ii][1]+=a*wv.y; acc[ii][2]+=a*wv.z; acc[ii][3]+=a*wv.w;
    }
  }
  #pragma unroll
  for (int ii=0; ii<4; ii++){
    int row = nb + n0 + ii;
    if (row < nrows){
      float4 v = make_float4(acc[ii][0],acc[ii][1],acc[ii][2],acc[ii][3]);
      *(float4*)&C[(size_t)row*128 + ch*64 + c0] = v;
    }
  }
}

// ---------------- per-node attention logit pieces ----------------
__global__ void k_anode1(const float* __restrict__ h, const float* __restrict__ as_,
                         const float* __restrict__ ad_, float* __restrict__ alphas,
                         float* __restrict__ alphad){
  int n = blockIdx.x, l = threadIdx.x; // 64 threads
  float h0 = h[(size_t)n*128 + l], h1 = h[(size_t)n*128 + 64 + l];
  float s0 = h0*as_[l], s1 = h1*as_[64+l];
  float d0 = h0*ad_[l], d1 = h1*ad_[64+l];
  for (int m=1;m<32;m<<=1){
    s0 += __shfl_xor(s0,m,64); s1 += __shfl_xor(s1,m,64);
    d0 += __shfl_xor(d0,m,64); d1 += __shfl_xor(d1,m,64);
  }
  if ((l&31)==0){
    int hh = l>>5;
    alphas[n*4+hh]   = s0; alphas[n*4+2+hh] = s1;
    alphad[n*4+hh]   = d0; alphad[n*4+2+hh] = d1;
  }
}

__global__ void k_anode2(const float* __restrict__ h, const float* __restrict__ as_,
                         const float* __restrict__ ad_, float* __restrict__ alphas,
                         float* __restrict__ alphad){
  int n = blockIdx.x, l = threadIdx.x;
  float h0 = h[(size_t)n*128+l], h1 = h[(size_t)n*128+64+l];
  float s = h0*as_[l] + h1*as_[64+l];
  float d = h0*ad_[l] + h1*ad_[64+l];
  for (int m=1;m<64;m<<=1){ s += __shfl_xor(s,m,64); d += __shfl_xor(d,m,64); }
  if (l==0){ alphas[n] = s; alphad[n] = d; }
}

// ---------------- fused CSR aggregation, layer 1 (4 heads) ----------------
__global__ __launch_bounds__(256) void k_agg1(
    const int* __restrict__ rowoff, const int* __restrict__ srcs,
    const float4* __restrict__ ae1p,
    const float* __restrict__ cst, int itype,
    const float* __restrict__ alphas, const float* __restrict__ alphad,
    const float* __restrict__ h, const float* __restrict__ b1, float* __restrict__ outn)
{
  int n = blockIdx.x*4 + (threadIdx.x>>6);
  if (n >= cN) return;
  int l = threadIdx.x & 63;
  int hlo = l>>5;          // head of channel l     (0 or 1)
  int hhi = 2 + hlo;       // head of channel l+64  (2 or 3)
  float ad_lo = alphad[n*4+hlo], ad_hi = alphad[n*4+hhi];
  // self-loop contribution
  float a_lo = alphas[n*4+hlo] + ad_lo + cst[K_LOOP1+itype*4+hlo];
  float a_hi = alphas[n*4+hhi] + ad_hi + cst[K_LOOP1+itype*4+hhi];
  a_lo = a_lo>0.f?a_lo:0.2f*a_lo; a_hi = a_hi>0.f?a_hi:0.2f*a_hi;
  float e_lo = expf(a_lo), e_hi = expf(a_hi);
  float den_lo = e_lo, den_hi = e_hi;
  float acc_lo = e_lo * h[(size_t)n*128 + l];
  float acc_hi = e_hi * h[(size_t)n*128 + 64 + l];
  int start = rowoff[n], end = rowoff[n+1];
  for (int cb = start; cb < end; cb += 64){
    int m = min(64, end-cb);
    int md_s = 0; float4 ma = make_float4(0.f,0.f,0.f,0.f);
    if (l < m){ md_s = srcs[cb+l]; ma = ae1p[cb+l]; }
    for (int t=0;t<m;t++){
      int s   = __shfl(md_s, t, 64);
      float ex = __shfl(ma.x, t, 64), ey = __shfl(ma.y, t, 64);
      float ez = __shfl(ma.z, t, 64), ew = __shfl(ma.w, t, 64);
      float ae_lo = hlo ? ey : ex;
      float ae_hi = hlo ? ew : ez;
      float al = alphas[s*4+hlo] + ad_lo + ae_lo;
      float ah = alphas[s*4+hhi] + ad_hi + ae_hi;
      al = al>0.f?al:0.2f*al; ah = ah>0.f?ah:0.2f*ah;
      float elo = expf(al), ehi = expf(ah);
      den_lo += elo; den_hi += ehi;
      acc_lo += elo * h[(size_t)s*128 + l];
      acc_hi += ehi * h[(size_t)s*128 + 64 + l];
    }
  }
  float vlo = acc_lo/(den_lo+1e-16f) + b1[l];
  float vhi = acc_hi/(den_hi+1e-16f) + b1[64+l];
  outn[(size_t)n*128+l]    = vlo>0.f?vlo:expm1f(vlo);   // ELU
  outn[(size_t)n*128+64+l] = vhi>0.f?vhi:expm1f(vhi);
}

// ---------------- fused CSR aggregation, layer 2 (1 head) + pooled scores ----------------
__global__ __launch_bounds__(256) void k_agg2(
    const int* __restrict__ rowoff, const int* __restrict__ srcs,
    const float* __restrict__ ae2p,
    const float* __restrict__ cst, int itype,
    const float* __restrict__ alphas, const float* __restrict__ alphad,
    const float* __restrict__ h, const float* __restrict__ b2, float* __restrict__ acc_out,
    const float* __restrict__ pw, const float* __restrict__ pb, float* __restrict__ es)
{
  int n = blockIdx.x*4 + (threadIdx.x>>6);
  if (n >= cN) return;
  int l = threadIdx.x & 63;
  float ad = alphad[n];
  float a = alphas[n] + ad + cst[K_LOOP2+itype];
  a = a>0.f?a:0.2f*a;
  float e = expf(a);
  float den = e;
  float acc_lo = e * h[(size_t)n*128 + l];
  float acc_hi = e * h[(size_t)n*128 + 64 + l];
  int start = rowoff[n], end = rowoff[n+1];
  for (int cb = start; cb < end; cb += 64){
    int m = min(64, end-cb);
    int md_s = 0; float ma = 0.f;
    if (l < m){ md_s = srcs[cb+l]; ma = ae2p[cb+l]; }
    for (int t=0;t<m;t++){
      int s   = __shfl(md_s, t, 64);
      float ae = __shfl(ma, t, 64);
      float al = alphas[s] + ad + ae;
      al = al>0.f?al:0.2f*al;
      float el = expf(al);
      den += el;
      acc_lo += el * h[(size_t)s*128 + l];
      acc_hi += el * h[(size_t)s*128 + 64 + l];
    }
  }
  float w = cst[K_WTS+itype];
  size_t o = (size_t)n*128 + l;
  float nv_lo = acc_out[o]    + w*(acc_lo/(den+1e-16f) + b2[l]);
  float nv_hi = acc_out[o+64] + w*(acc_hi/(den+1e-16f) + b2[64+l]);
  acc_out[o]    = nv_lo;
  acc_out[o+64] = nv_hi;
  if (itype == 2 && n >= cR){
    float s = nv_lo*pw[l] + nv_hi*pw[64+l];
    for (int m=1;m<64;m<<=1) s += __shfl_xor(s,m,64);
    if (l==0) es[n-cR] = expf(s + pb[0]);
  }
}

// ---------------- pooling: pn[64][128] = W[64][V] @ veh[V][128], denp[r]=row-sum ----------------
// 4 chunks of 64 v per block; partials accumulate in registers, atomics once at end.
constexpr int VC  = 64;
constexpr int NCH = 4;
__global__ __launch_bounds__(256) void k_pool(const int* __restrict__ mask,
        const float* __restrict__ es, const float* __restrict__ acc,
        float* __restrict__ pn, float* __restrict__ denp){
  __shared__ float w[64][VC];
  int t = threadIdx.x;
  int c = t & 127, rh = t >> 7;
  const float* veh = acc + (size_t)cR*128;
  float a[32];
  #pragma unroll
  for (int i2=0;i2<32;i2++) a[i2]=0.f;
  float dsum = 0.f;
  int rd = t >> 2, seg = t & 3, lane = t & 63;
  for (int chk = 0; chk < NCH; chk++){
    int base = (blockIdx.x*NCH + chk)*VC;
    if (base >= cV) break;                     // uniform across block
    #pragma unroll
    for (int k=0;k<16;k++){
      int idx = k*256 + t;
      int r = idx >> 6, vv = idx & 63;
      int v = base + vv;
      float wv = 0.f;
      if (v < cV){ if (mask[(size_t)r*cV + v]) wv = es[v]; }
      w[r][vv] = wv;
    }
    __syncthreads();
    // denp partial (skewed reads: 2 lanes/bank = free)
    #pragma unroll
    for (int j=0;j<16;j++){
      int vv = seg*16 + ((j + lane) & 15);
      dsum += w[rd][vv];
    }
    // main: thread owns channel c for 32 r's
    #pragma unroll 2
    for (int vv=0; vv<VC; vv+=4){
      int v0 = base + vv;
      int vl0 = min(v0+0, cV-1), vl1 = min(v0+1, cV-1);
      int vl2 = min(v0+2, cV-1), vl3 = min(v0+3, cV-1);
      float h0 = veh[(size_t)vl0*128 + c];
      float h1 = veh[(size_t)vl1*128 + c];
      float h2 = veh[(size_t)vl2*128 + c];
      float h3 = veh[(size_t)vl3*128 + c];
      #pragma unroll
      for (int rr=0; rr<32; rr++){
        float4 w4 = *(const float4*)&w[rh*32+rr][vv];   // broadcast b128
        a[rr] += w4.x*h0 + w4.y*h1 + w4.z*h2 + w4.w*h3;
      }
    }
    __syncthreads();
  }
  dsum += __shfl_xor(dsum, 1, 64);
  dsum += __shfl_xor(dsum, 2, 64);
  if (seg == 0) atomicAdd(&denp[rd], dsum);
  #pragma unroll
  for (int rr=0; rr<32; rr++)
    atomicAdd(&pn[(rh*32+rr)*128 + c], a[rr]);
}

// ---------------- head MLP ----------------
__global__ __launch_bounds__(128) void k_mlp(const float* __restrict__ acc, const float* __restrict__ pn,
                     const float* __restrict__ denp,
                     const float* __restrict__ Wo1, const float* __restrict__ bo1,
                     const float* __restrict__ Wo2, const float* __restrict__ bo2,
                     const float* __restrict__ Wo3, const float* __restrict__ bo3,
                     float* __restrict__ dout){
  __shared__ float comb[256], q1[128], q2[64];
  int r = blockIdx.x, t = threadIdx.x;
  comb[t] = acc[(size_t)r*128 + t];
  float dp = denp[r];
  comb[128+t] = dp > 0.f ? pn[r*128+t]/dp : 0.f;
  __syncthreads();
  float s = bo1[t];
  for (int k=0;k<256;k++) s += comb[k]*Wo1[k*128+t];
  q1[t] = fmaxf(s, 0.f);
  __syncthreads();
  if (t < 64){
    float s2 = bo2[t];
    for (int k=0;k<128;k++) s2 += q1[k]*Wo2[k*64+t];
    q2[t] = fmaxf(s2, 0.f);
  }
  __syncthreads();
  if (t < 16){
    float s3 = bo3[t];
    for (int k=0;k<64;k++) s3 += q2[k]*Wo3[k*16+t];
    dout[r*16+t] = s3;
  }
}

// ---------------- launcher ----------------
extern "C" void kernel_launch(void* const* d_in, const int* in_sizes, int n_in,
                              void* d_out, int out_size, void* d_ws, size_t ws_size,
                              hipStream_t stream){
  const float* nf   = (const float*)d_in[0];
  const float* ea[3]= {(const float*)d_in[1],(const float*)d_in[2],(const float*)d_in[3]};
  const float* te   = (const float*)d_in[4];
  const float* etg  = (const float*)d_in[5];
  const float* eta  = (const float*)d_in[6];
  const float* W1   = (const float*)d_in[7];
  const float* as1  = (const float*)d_in[8];
  const float* ad1  = (const float*)d_in[9];
  const float* We1  = (const float*)d_in[10];
  const float* ae1  = (const float*)d_in[11];
  const float* b1   = (const float*)d_in[12];
  const float* W2   = (const float*)d_in[13];
  const float* as2  = (const float*)d_in[14];
  const float* ad2  = (const float*)d_in[15];
  const float* We2  = (const float*)d_in[16];
  const float* ae2  = (const float*)d_in[17];
  const float* b2   = (const float*)d_in[18];
  const float* pw   = (const float*)d_in[19];
  const float* pb   = (const float*)d_in[20];
  const float* Wo1  = (const float*)d_in[21];
  const float* bo1  = (const float*)d_in[22];
  const float* Wo2  = (const float*)d_in[23];
  const float* bo2  = (const float*)d_in[24];
  const float* Wo3  = (const float*)d_in[25];
  const float* bo3  = (const float*)d_in[26];
  const int*  nt    = (const int*)d_in[27];
  const int*  ei[3] = {(const int*)d_in[28],(const int*)d_in[29],(const int*)d_in[30]};
  const int*  cmask = (const int*)d_in[31];

  float* ws  = (float*)d_ws;
  float* out = (float*)d_out;

  float* cst  = ws;
  float* x0   = ws + OFF_X0;
  float* h    = ws + OFF_H;
  float* outn = ws + OFF_OUT;
  float* acc  = ws + OFF_ACC;
  float* as_  = ws + OFF_AS;
  float* ad_  = ws + OFF_AD;
  float* es   = ws + OFF_ES;
  float* pn   = ws + OFF_PN;
  float* denp = ws + OFF_DENP;
  int* rowoff = (int*)(ws + OFF_ROWOFF);
  int* deg    = (int*)(ws + OFF_DEG);
  int* cnt    = (int*)(ws + OFF_CNT);
  int* srcs   = (int*)(ws + OFF_SRCS);
  float4* ae1p= (float4*)(ws + OFF_AE1);
  float* ae2p = ws + OFF_AE2;
  int* bsum   = (int*)(ws + OFF_BSUM);
  int* boff   = (int*)(ws + OFF_BOFF);

  hipMemsetAsync(cst, 0, 1024*sizeof(float), stream);
  hipMemsetAsync(acc, 0, (size_t)cN*128*sizeof(float), stream);
  hipMemsetAsync(pn,  0, ((size_t)cR*128 + cR)*sizeof(float), stream);

  k_setup<<<1,128,0,stream>>>(etg, eta, We1, ae1, We2, ae2, cst, out);
  k_eamean<<<dim3(64,3),256,0,stream>>>(ea[0],ea[1],ea[2],cst);
  k_loopconsts<<<1,16,0,stream>>>(cst);
  k_x0<<<cN,64,0,stream>>>(nf, te, nt, x0);

  const int egrid = (cE+255)/256;
  const int ngrid = (cN+3)/4;
  const int ntile = (cN+1023)/1024;   // 49

  for (int i=0;i<3;i++){
    const int* src = ei[i];
    const int* dst = ei[i] + cE;
    // ---- CSR build (shared by both layers of this type) ----
    hipMemsetAsync(deg, 0, (size_t)2*cN*sizeof(int), stream);   // deg + cnt contiguous
    k_deg<<<egrid,256,0,stream>>>(dst, deg);
    k_bsum<<<ntile,1024,0,stream>>>(deg, bsum);
    k_bscan<<<1,64,0,stream>>>(bsum, boff);
    k_tilescan<<<ntile,1024,0,stream>>>(deg, boff, rowoff);
    k_scatter<<<egrid,256,0,stream>>>(src, dst, ea[i], cst, i, rowoff, cnt, srcs, ae1p, ae2p);
    // ---- layer 1 ----
    k_gemm<41,44><<<dim3((cN+63)/64,2),256,0,stream>>>(x0, W1 + (size_t)i*41*128, h, cN);
    k_anode1<<<cN,64,0,stream>>>(h, as1 + i*128, ad1 + i*128, as_, ad_);
    k_agg1<<<ngrid,256,0,stream>>>(rowoff, srcs, ae1p, cst, i, as_, ad_, h, b1 + i*128, outn);
    // ---- layer 2 ----
    k_gemm<128,128><<<dim3((cN+63)/64,2),256,0,stream>>>(outn, W2 + (size_t)i*128*128, h, cN);
    k_anode2<<<cN,64,0,stream>>>(h, as2 + i*128, ad2 + i*128, as_, ad_);
    k_agg2<<<ngrid,256,0,stream>>>(rowoff, srcs, ae2p, cst, i, as_, ad_, h, b2 + i*128, acc,
                                   pw, pb, es);
  }

  k_pool<<<(cV+VC*NCH-1)/(VC*NCH),256,0,stream>>>(cmask, es, acc, pn, denp);
  k_mlp<<<cR,128,0,stream>>>(acc, pn, denp, Wo1, bo1, Wo2, bo2, Wo3, bo3, out);
}

// Round 6
// 1290.303 us; speedup vs baseline: 2.3486x; 1.0515x over previous
//
#include <hip/hip_runtime.h>
#include <math.h>

// ---------------- problem constants ----------------
constexpr int cN  = 50000;
constexpr int cE  = 600000;
constexpr int cR  = 64;
constexpr int cV  = cN - cR;     // 49936
constexpr int cNF = 9;
constexpr int cIN = 41;          // 9 + 32

// ---------------- const-region sub-offsets (floats) ----------------
constexpr int K_GATES = 0;    // 3
constexpr int K_WTS   = 3;    // 3
constexpr int K_LOOP1 = 6;    // 3*4
constexpr int K_LOOP2 = 18;   // 3
constexpr int K_VE1   = 32;   // 3*8*4
constexpr int K_VE2   = 128;  // 3*8
constexpr int K_EASUM = 160;  // 3*8

// ---------------- ws layout (float units) ----------------
constexpr size_t OFF_X0    = 1024;
constexpr size_t OFF_H     = OFF_X0  + 2050048;   // x0: 50000*41 = 2,050,000 (padded)
constexpr size_t OFF_OUT   = OFF_H   + 6400000;
constexpr size_t OFF_ACC   = OFF_OUT + 6400000;
constexpr size_t OFF_AS    = OFF_ACC + 6400000;   // 200,000
constexpr size_t OFF_AD    = OFF_AS  + 200000;    // 200,000
constexpr size_t OFF_ES    = OFF_AD  + 200000;    // 50,048
constexpr size_t OFF_PN    = OFF_ES  + 50048;     // 8192
constexpr size_t OFF_DENP  = OFF_PN  + 8192;      // 64
constexpr size_t OFF_ROWOFF= OFF_DENP+ 64;        // int cN+1 -> 50,016
constexpr size_t OFF_DEG   = OFF_ROWOFF + 50016;  // int cN
constexpr size_t OFF_CNT   = OFF_DEG + 50000;     // int cN (contiguous with DEG)
constexpr size_t OFF_SRCS  = OFF_CNT + 50000;     // int cE
constexpr size_t OFF_AE1   = OFF_SRCS+ 600000;    // float4 * cE  (16B aligned)
constexpr size_t OFF_AE2   = OFF_AE1 + 2400000;   // float cE
constexpr size_t OFF_BSUM  = OFF_AE2 + 600000;    // int 64
constexpr size_t OFF_BOFF  = OFF_BSUM+ 64;        // int 64
// total ~25.46M floats = ~102 MB

// ---------------- small setup kernels ----------------
__global__ void k_setup(const float* __restrict__ etg, const float* __restrict__ eta,
                        const float* __restrict__ We1, const float* __restrict__ ae1,
                        const float* __restrict__ We2, const float* __restrict__ ae2,
                        float* __restrict__ cst, float* __restrict__ dout){
  int t = threadIdx.x; // 128 threads
  if (t < 3){
    cst[K_GATES+t] = 1.f/(1.f+expf(-etg[t]));
    float m = fmaxf(fmaxf(eta[0],eta[1]),eta[2]);
    float e0=expf(eta[0]-m), e1=expf(eta[1]-m), e2=expf(eta[2]-m);
    cst[K_WTS+t] = expf(eta[t]-m)/(e0+e1+e2);
    dout[1024+t] = eta[t];       // second tuple output
  }
  if (t < 96){ // ve1[(i*8+k)*4+h] = sum_c We1[i,k,h*32+c]*ae1[i,h,c]
    int i = t >> 5, k = (t>>2)&7, h = t&3;
    const float* w = We1 + ((size_t)(i*8+k))*128 + h*32;
    const float* a = ae1 + (i*4+h)*32;
    float s = 0.f;
    for (int c=0;c<32;c++) s += w[c]*a[c];
    cst[K_VE1 + t] = s;
  }
  if (t < 24){ // ve2[i*8+k] = sum_c We2[i,k,c]*ae2[i,c]
    int i = t >> 3, k = t & 7;
    const float* w = We2 + ((size_t)(i*8+k))*128;
    const float* a = ae2 + i*128;
    float s = 0.f;
    for (int c=0;c<128;c++) s += w[c]*a[c];
    cst[K_VE2 + t] = s;
  }
}

__global__ void k_eamean(const float* __restrict__ ea0, const float* __restrict__ ea1,
                         const float* __restrict__ ea2, float* __restrict__ cst){
  int i = blockIdx.y;
  const float* ea = (i==0)?ea0:(i==1)?ea1:ea2;
  float s[8];
  #pragma unroll
  for (int k=0;k<8;k++) s[k]=0.f;
  for (int e = blockIdx.x*blockDim.x + threadIdx.x; e < cE; e += gridDim.x*blockDim.x){
    const float4* p = (const float4*)(ea + (size_t)e*8);
    float4 a = p[0], b = p[1];
    s[0]+=a.x; s[1]+=a.y; s[2]+=a.z; s[3]+=a.w;
    s[4]+=b.x; s[5]+=b.y; s[6]+=b.z; s[7]+=b.w;
  }
  for (int m=1;m<64;m<<=1){
    #pragma unroll
    for (int k=0;k<8;k++) s[k] += __shfl_xor(s[k], m, 64);
  }
  if ((threadIdx.x & 63) == 0){
    #pragma unroll
    for (int k=0;k<8;k++) atomicAdd(&cst[K_EASUM + i*8 + k], s[k]);
  }
}

__global__ void k_loopconsts(float* __restrict__ cst){
  int t = threadIdx.x;
  if (t < 12){
    int i=t>>2, h=t&3;
    float s=0.f;
    for (int k=0;k<8;k++) s += (cst[K_EASUM+i*8+k]/(float)cE)*cst[K_VE1+(i*8+k)*4+h];
    cst[K_LOOP1+t] = cst[K_GATES+i]*s;
  } else if (t < 15){
    int i=t-12; float s=0.f;
    for (int k=0;k<8;k++) s += (cst[K_EASUM+i*8+k]/(float)cE)*cst[K_VE2+i*8+k];
    cst[K_LOOP2+i] = cst[K_GATES+i]*s;
  }
}

__global__ void k_x0(const float* __restrict__ nf, const float* __restrict__ te,
                     const int* __restrict__ nt, float* __restrict__ x0){
  int n = blockIdx.x, j = threadIdx.x;
  if (j >= cIN) return;
  float v = (j < cNF) ? nf[(size_t)n*cNF + j] : te[nt[n]*32 + (j-cNF)];
  x0[(size_t)n*cIN + j] = v;
}

// ---------------- CSR build ----------------
__global__ void k_deg(const int* __restrict__ dst, int* __restrict__ deg){
  int e = blockIdx.x*256 + threadIdx.x;
  if (e < cE) atomicAdd(&deg[dst[e]], 1);
}

__global__ __launch_bounds__(1024) void k_bsum(const int* __restrict__ deg, int* __restrict__ bsum){
  int b=blockIdx.x, t=threadIdx.x, i=b*1024+t;
  int v=(i<cN)?deg[i]:0;
  for(int m=1;m<64;m<<=1) v += __shfl_xor(v,m,64);
  __shared__ int wsm[16];
  if((t&63)==0) wsm[t>>6]=v;
  __syncthreads();
  if(t==0){int s=0; for(int k=0;k<16;k++) s+=wsm[k]; bsum[b]=s;}
}

__global__ void k_bscan(const int* __restrict__ bsum, int* __restrict__ boff){
  int t = threadIdx.x;           // 64 threads, 49 tiles
  int v = (t<49)? bsum[t] : 0;
  int x = v;
  for (int off=1; off<64; off<<=1){
    int y = __shfl_up(x, off, 64);
    if (t>=off) x += y;
  }
  if (t<49) boff[t] = x - v;     // exclusive tile offsets
}

__global__ __launch_bounds__(1024) void k_tilescan(const int* __restrict__ deg,
                        const int* __restrict__ boff, int* __restrict__ rowoff){
  __shared__ int sa[1024], sb[1024];
  int b = blockIdx.x, t = threadIdx.x;
  int i = b*1024 + t;
  int v = (i<cN)? deg[i] : 0;
  sa[t] = v; __syncthreads();
  int* cur = sa; int* nxt = sb;
  for (int off=1; off<1024; off<<=1){
    int x = cur[t];
    if (t>=off) x += cur[t-off];
    nxt[t] = x;
    __syncthreads();
    int* tmp=cur; cur=nxt; nxt=tmp;
  }
  if (i<cN) rowoff[i] = boff[b] + cur[t] - v;   // exclusive
  if (i==cN-1) rowoff[cN] = cE;
}

// fused scatter: CSR placement + per-edge logit consts (ea read once, coalesced)
__global__ void k_scatter(const int* __restrict__ src, const int* __restrict__ dst,
                          const float* __restrict__ ea, const float* __restrict__ cst, int itype,
                          const int* __restrict__ rowoff, int* __restrict__ cnt,
                          int* __restrict__ srcs, float4* __restrict__ ae1p,
                          float* __restrict__ ae2p){
  int e = blockIdx.x*256 + threadIdx.x;
  if (e >= cE) return;
  int d = dst[e];
  int p = rowoff[d] + atomicAdd(&cnt[d], 1);
  srcs[p] = src[e];
  const float4* eap = (const float4*)(ea + (size_t)e*8);
  float4 u = eap[0], v = eap[1];
  float ew[8] = {u.x,u.y,u.z,u.w,v.x,v.y,v.z,v.w};
  float g = cst[K_GATES+itype];
  float a1x=0,a1y=0,a1z=0,a1w=0,a2=0;
  #pragma unroll
  for (int k=0;k<8;k++){
    float evk = ew[k];
    const float* vp = &cst[K_VE1+(itype*8+k)*4];
    a1x += evk*vp[0]; a1y += evk*vp[1]; a1z += evk*vp[2]; a1w += evk*vp[3];
    a2  += evk*cst[K_VE2+itype*8+k];
  }
  ae1p[p] = make_float4(g*a1x, g*a1y, g*a1z, g*a1w);
  ae2p[p] = g*a2;
}

// ---------------- GEMM ----------------
template<int K, int KS>
__global__ __launch_bounds__(256) void k_gemm(const float* __restrict__ A,
                                              const float* __restrict__ B,
                                              float* __restrict__ C, int nrows){
  __shared__ float sA[64][KS];
  __shared__ float sB[K][64];
  const int tid = threadIdx.x;
  const int nb = blockIdx.x * 64;
  const int ch = blockIdx.y;
  for (int idx = tid; idx < 64*K; idx += 256){
    int n = idx / K, k = idx - n*K;
    int row = nb + n; if (row >= nrows) row = nrows - 1;
    sA[n][k] = A[(size_t)row*K + k];
  }
  for (int idx = tid; idx < K*64; idx += 256){
    int k = idx >> 6, c = idx & 63;
    sB[k][c] = B[k*128 + ch*64 + c];
  }
  __syncthreads();
  const int cg = tid & 15, ng = tid >> 4;
  const int c0 = cg*4, n0 = ng*4;
  float acc[4][4] = {};
  int k = 0;
  for (; k + 4 <= K; k += 4){
    float4 a4[4], w4[4];
    #pragma unroll
    for (int ii=0; ii<4; ii++) a4[ii] = *(const float4*)&sA[n0+ii][k];
    #pragma unroll
    for (int kk=0; kk<4; kk++) w4[kk] = *(const float4*)&sB[k+kk][c0];
    const float* ap = (const float*)a4;
    const float* wp = (const float*)w4;
    #pragma unroll
    for (int ii=0; ii<4; ii++)
      #pragma unroll
      for (int kk=0; kk<4; kk++)
        #pragma unroll
        for (int jj=0; jj<4; jj++)
          acc[ii][jj] += ap[ii*4+kk]*wp[kk*4+jj];
  }
  for (; k < K; k++){
    float4 wv = *(const float4*)&sB[k][c0];
    #pragma unroll
    for (int ii=0; ii<4; ii++){
      float a = sA[n0+ii][k];
      acc[ii][0]+=a*wv.x; acc[ii][1]+=a*wv.y; acc[ii][2]+=a*wv.z; acc[ii][3]+=a*wv.w;
    }
  }
  #pragma unroll
  for (int ii=0; ii<4; ii++){
    int row = nb + n0 + ii;
    if (row < nrows){
      float4 v = make_float4(acc[ii][0],acc[ii][1],acc[ii][2],acc[ii][3]);
      *(float4*)&C[(size_t)row*128 + ch*64 + c0] = v;
    }
  }
}

// ---------------- per-node attention logit pieces ----------------
__global__ void k_anode1(const float* __restrict__ h, const float* __restrict__ as_,
                         const float* __restrict__ ad_, float* __restrict__ alphas,
                         float* __restrict__ alphad){
  int n = blockIdx.x, l = threadIdx.x; // 64 threads
  float h0 = h[(size_t)n*128 + l], h1 = h[(size_t)n*128 + 64 + l];
  float s0 = h0*as_[l], s1 = h1*as_[64+l];
  float d0 = h0*ad_[l], d1 = h1*ad_[64+l];
  for (int m=1;m<32;m<<=1){
    s0 += __shfl_xor(s0,m,64); s1 += __shfl_xor(s1,m,64);
    d0 += __shfl_xor(d0,m,64); d1 += __shfl_xor(d1,m,64);
  }
  if ((l&31)==0){
    int hh = l>>5;
    alphas[n*4+hh]   = s0; alphas[n*4+2+hh] = s1;
    alphad[n*4+hh]   = d0; alphad[n*4+2+hh] = d1;
  }
}

__global__ void k_anode2(const float* __restrict__ h, const float* __restrict__ as_,
                         const float* __restrict__ ad_, float* __restrict__ alphas,
                         float* __restrict__ alphad){
  int n = blockIdx.x, l = threadIdx.x;
  float h0 = h[(size_t)n*128+l], h1 = h[(size_t)n*128+64+l];
  float s = h0*as_[l] + h1*as_[64+l];
  float d = h0*ad_[l] + h1*ad_[64+l];
  for (int m=1;m<64;m<<=1){ s += __shfl_xor(s,m,64); d += __shfl_xor(d,m,64); }
  if (l==0){ alphas[n] = s; alphad[n] = d; }
}

// ---------------- fused CSR aggregation, layer 1 (4 heads) ----------------
__global__ __launch_bounds__(256) void k_agg1(
    const int* __restrict__ rowoff, const int* __restrict__ srcs,
    const float4* __restrict__ ae1p,
    const float* __restrict__ cst, int itype,
    const float* __restrict__ alphas, const float* __restrict__ alphad,
    const float* __restrict__ h, const float* __restrict__ b1, float* __restrict__ outn)
{
  int n = blockIdx.x*4 + (threadIdx.x>>6);
  if (n >= cN) return;
  int l = threadIdx.x & 63;
  int hlo = l>>5;          // head of channel l     (0 or 1)
  int hhi = 2 + hlo;       // head of channel l+64  (2 or 3)
  float ad_lo = alphad[n*4+hlo], ad_hi = alphad[n*4+hhi];
  // self-loop contribution
  float a_lo = alphas[n*4+hlo] + ad_lo + cst[K_LOOP1+itype*4+hlo];
  float a_hi = alphas[n*4+hhi] + ad_hi + cst[K_LOOP1+itype*4+hhi];
  a_lo = a_lo>0.f?a_lo:0.2f*a_lo; a_hi = a_hi>0.f?a_hi:0.2f*a_hi;
  float e_lo = expf(a_lo), e_hi = expf(a_hi);
  float den_lo = e_lo, den_hi = e_hi;
  float acc_lo = e_lo * h[(size_t)n*128 + l];
  float acc_hi = e_hi * h[(size_t)n*128 + 64 + l];
  int start = rowoff[n], end = rowoff[n+1];
  for (int cb = start; cb < end; cb += 64){
    int m = min(64, end-cb);
    int md_s = 0; float4 ma = make_float4(0.f,0.f,0.f,0.f);
    if (l < m){ md_s = srcs[cb+l]; ma = ae1p[cb+l]; }
    for (int t=0;t<m;t++){
      int s   = __shfl(md_s, t, 64);
      float ex = __shfl(ma.x, t, 64), ey = __shfl(ma.y, t, 64);
      float ez = __shfl(ma.z, t, 64), ew = __shfl(ma.w, t, 64);
      float ae_lo = hlo ? ey : ex;
      float ae_hi = hlo ? ew : ez;
      float al = alphas[s*4+hlo] + ad_lo + ae_lo;
      float ah = alphas[s*4+hhi] + ad_hi + ae_hi;
      al = al>0.f?al:0.2f*al; ah = ah>0.f?ah:0.2f*ah;
      float elo = expf(al), ehi = expf(ah);
      den_lo += elo; den_hi += ehi;
      acc_lo += elo * h[(size_t)s*128 + l];
      acc_hi += ehi * h[(size_t)s*128 + 64 + l];
    }
  }
  float vlo = acc_lo/(den_lo+1e-16f) + b1[l];
  float vhi = acc_hi/(den_hi+1e-16f) + b1[64+l];
  outn[(size_t)n*128+l]    = vlo>0.f?vlo:expm1f(vlo);   // ELU
  outn[(size_t)n*128+64+l] = vhi>0.f?vhi:expm1f(vhi);
}

// ---------------- fused CSR aggregation, layer 2 (1 head) + pooled scores ----------------
// itype==0 WRITES acc_out (no prior memset needed); itype>0 accumulates.
__global__ __launch_bounds__(256) void k_agg2(
    const int* __restrict__ rowoff, const int* __restrict__ srcs,
    const float* __restrict__ ae2p,
    const float* __restrict__ cst, int itype,
    const float* __restrict__ alphas, const float* __restrict__ alphad,
    const float* __restrict__ h, const float* __restrict__ b2, float* __restrict__ acc_out,
    const float* __restrict__ pw, const float* __restrict__ pb, float* __restrict__ es)
{
  int n = blockIdx.x*4 + (threadIdx.x>>6);
  if (n >= cN) return;
  int l = threadIdx.x & 63;
  float ad = alphad[n];
  float a = alphas[n] + ad + cst[K_LOOP2+itype];
  a = a>0.f?a:0.2f*a;
  float e = expf(a);
  float den = e;
  float acc_lo = e * h[(size_t)n*128 + l];
  float acc_hi = e * h[(size_t)n*128 + 64 + l];
  int start = rowoff[n], end = rowoff[n+1];
  for (int cb = start; cb < end; cb += 64){
    int m = min(64, end-cb);
    int md_s = 0; float ma = 0.f;
    if (l < m){ md_s = srcs[cb+l]; ma = ae2p[cb+l]; }
    for (int t=0;t<m;t++){
      int s   = __shfl(md_s, t, 64);
      float ae = __shfl(ma, t, 64);
      float al = alphas[s] + ad + ae;
      al = al>0.f?al:0.2f*al;
      float el = expf(al);
      den += el;
      acc_lo += el * h[(size_t)s*128 + l];
      acc_hi += el * h[(size_t)s*128 + 64 + l];
    }
  }
  float w = cst[K_WTS+itype];
  size_t o = (size_t)n*128 + l;
  float base_lo = (itype==0) ? 0.f : acc_out[o];
  float base_hi = (itype==0) ? 0.f : acc_out[o+64];
  float nv_lo = base_lo + w*(acc_lo/(den+1e-16f) + b2[l]);
  float nv_hi = base_hi + w*(acc_hi/(den+1e-16f) + b2[64+l]);
  acc_out[o]    = nv_lo;
  acc_out[o+64] = nv_hi;
  if (itype == 2 && n >= cR){
    float s = nv_lo*pw[l] + nv_hi*pw[64+l];
    for (int m=1;m<64;m<<=1) s += __shfl_xor(s,m,64);
    if (l==0) es[n-cR] = expf(s + pb[0]);
  }
}

// ---------------- pooling: pn[64][128] = W[64][V] @ veh[V][128], denp[r]=row-sum ----------------
// 781 blocks x 512 threads; each block owns 64 v's; thread owns 1 channel x 16 r's.
constexpr int VC = 64;
__global__ __launch_bounds__(512) void k_pool(const int* __restrict__ mask,
        const float* __restrict__ es, const float* __restrict__ acc,
        float* __restrict__ pn, float* __restrict__ denp){
  __shared__ float w[64][VC];                  // 16 KB
  int t = threadIdx.x;
  int base = blockIdx.x*VC;
  // stage mask*es: 4096 entries, 8 per thread, coalesced over vv
  #pragma unroll
  for (int k=0;k<8;k++){
    int idx = k*512 + t;
    int r = idx >> 6, vv = idx & 63;
    int v = base + vv;
    float wv = 0.f;
    if (v < cV){ if (mask[(size_t)r*cV + v]) wv = es[v]; }
    w[r][vv] = wv;
  }
  __syncthreads();
  // denp partials: threads < 256, 4 threads per r, skewed cols (conflict-light)
  if (t < 256){
    int rd = t >> 2, seg = t & 3, lane = t & 63;
    float dsum = 0.f;
    #pragma unroll
    for (int j=0;j<16;j++){
      int vv = seg*16 + ((j + lane) & 15);
      dsum += w[rd][vv];
    }
    dsum += __shfl_xor(dsum, 1, 64);
    dsum += __shfl_xor(dsum, 2, 64);
    if (seg == 0) atomicAdd(&denp[rd], dsum);
  }
  // main: thread owns channel c for 16 r's (rh = wave-pair id, uniform per wave)
  int c = t & 127, rh = t >> 7;                // rh in 0..3
  const float* veh = acc + (size_t)cR*128;
  float a[16];
  #pragma unroll
  for (int i2=0;i2<16;i2++) a[i2]=0.f;
  #pragma unroll 4
  for (int vv=0; vv<VC; vv+=4){
    int v0 = base + vv;
    int vl0 = min(v0+0, cV-1), vl1 = min(v0+1, cV-1);
    int vl2 = min(v0+2, cV-1), vl3 = min(v0+3, cV-1);
    float h0 = veh[(size_t)vl0*128 + c];
    float h1 = veh[(size_t)vl1*128 + c];
    float h2 = veh[(size_t)vl2*128 + c];
    float h3 = veh[(size_t)vl3*128 + c];
    #pragma unroll
    for (int rr=0; rr<16; rr++){
      float4 w4 = *(const float4*)&w[rh*16+rr][vv];   // wave-uniform broadcast
      a[rr] += w4.x*h0 + w4.y*h1 + w4.z*h2 + w4.w*h3;
    }
  }
  #pragma unroll
  for (int rr=0; rr<16; rr++)
    atomicAdd(&pn[(rh*16+rr)*128 + c], a[rr]);
}

// ---------------- head MLP ----------------
__global__ __launch_bounds__(128) void k_mlp(const float* __restrict__ acc, const float* __restrict__ pn,
                     const float* __restrict__ denp,
                     const float* __restrict__ Wo1, const float* __restrict__ bo1,
                     const float* __restrict__ Wo2, const float* __restrict__ bo2,
                     const float* __restrict__ Wo3, const float* __restrict__ bo3,
                     float* __restrict__ dout){
  __shared__ float comb[256], q1[128], q2[64];
  int r = blockIdx.x, t = threadIdx.x;
  comb[t] = acc[(size_t)r*128 + t];
  float dp = denp[r];
  comb[128+t] = dp > 0.f ? pn[r*128+t]/dp : 0.f;
  __syncthreads();
  float s = bo1[t];
  for (int k=0;k<256;k++) s += comb[k]*Wo1[k*128+t];
  q1[t] = fmaxf(s, 0.f);
  __syncthreads();
  if (t < 64){
    float s2 = bo2[t];
    for (int k=0;k<128;k++) s2 += q1[k]*Wo2[k*64+t];
    q2[t] = fmaxf(s2, 0.f);
  }
  __syncthreads();
  if (t < 16){
    float s3 = bo3[t];
    for (int k=0;k<64;k++) s3 += q2[k]*Wo3[k*16+t];
    dout[r*16+t] = s3;
  }
}

// ---------------- launcher ----------------
extern "C" void kernel_launch(void* const* d_in, const int* in_sizes, int n_in,
                              void* d_out, int out_size, void* d_ws, size_t ws_size,
                              hipStream_t stream){
  const float* nf   = (const float*)d_in[0];
  const float* ea[3]= {(const float*)d_in[1],(const float*)d_in[2],(const float*)d_in[3]};
  const float* te   = (const float*)d_in[4];
  const float* etg  = (const float*)d_in[5];
  const float* eta  = (const float*)d_in[6];
  const float* W1   = (const float*)d_in[7];
  const float* as1  = (const float*)d_in[8];
  const float* ad1  = (const float*)d_in[9];
  const float* We1  = (const float*)d_in[10];
  const float* ae1  = (const float*)d_in[11];
  const float* b1   = (const float*)d_in[12];
  const float* W2   = (const float*)d_in[13];
  const float* as2  = (const float*)d_in[14];
  const float* ad2  = (const float*)d_in[15];
  const float* We2  = (const float*)d_in[16];
  const float* ae2  = (const float*)d_in[17];
  const float* b2   = (const float*)d_in[18];
  const float* pw   = (const float*)d_in[19];
  const float* pb   = (const float*)d_in[20];
  const float* Wo1  = (const float*)d_in[21];
  const float* bo1  = (const float*)d_in[22];
  const float* Wo2  = (const float*)d_in[23];
  const float* bo2  = (const float*)d_in[24];
  const float* Wo3  = (const float*)d_in[25];
  const float* bo3  = (const float*)d_in[26];
  const int*  nt    = (const int*)d_in[27];
  const int*  ei[3] = {(const int*)d_in[28],(const int*)d_in[29],(const int*)d_in[30]};
  const int*  cmask = (const int*)d_in[31];

  float* ws  = (float*)d_ws;
  float* out = (float*)d_out;

  float* cst  = ws;
  float* x0   = ws + OFF_X0;
  float* h    = ws + OFF_H;
  float* outn = ws + OFF_OUT;
  float* acc  = ws + OFF_ACC;
  float* as_  = ws + OFF_AS;
  float* ad_  = ws + OFF_AD;
  float* es   = ws + OFF_ES;
  float* pn   = ws + OFF_PN;
  float* denp = ws + OFF_DENP;
  int* rowoff = (int*)(ws + OFF_ROWOFF);
  int* deg    = (int*)(ws + OFF_DEG);
  int* cnt    = (int*)(ws + OFF_CNT);
  int* srcs   = (int*)(ws + OFF_SRCS);
  float4* ae1p= (float4*)(ws + OFF_AE1);
  float* ae2p = ws + OFF_AE2;
  int* bsum   = (int*)(ws + OFF_BSUM);
  int* boff   = (int*)(ws + OFF_BOFF);

  hipMemsetAsync(cst, 0, 1024*sizeof(float), stream);
  hipMemsetAsync(pn,  0, ((size_t)cR*128 + cR)*sizeof(float), stream);

  k_setup<<<1,128,0,stream>>>(etg, eta, We1, ae1, We2, ae2, cst, out);
  k_eamean<<<dim3(64,3),256,0,stream>>>(ea[0],ea[1],ea[2],cst);
  k_loopconsts<<<1,16,0,stream>>>(cst);
  k_x0<<<cN,64,0,stream>>>(nf, te, nt, x0);

  const int egrid = (cE+255)/256;
  const int ngrid = (cN+3)/4;
  const int ntile = (cN+1023)/1024;   // 49

  for (int i=0;i<3;i++){
    const int* src = ei[i];
    const int* dst = ei[i] + cE;
    // ---- CSR build (shared by both layers of this type) ----
    hipMemsetAsync(deg, 0, (size_t)2*cN*sizeof(int), stream);   // deg + cnt contiguous
    k_deg<<<egrid,256,0,stream>>>(dst, deg);
    k_bsum<<<ntile,1024,0,stream>>>(deg, bsum);
    k_bscan<<<1,64,0,stream>>>(bsum, boff);
    k_tilescan<<<ntile,1024,0,stream>>>(deg, boff, rowoff);
    k_scatter<<<egrid,256,0,stream>>>(src, dst, ea[i], cst, i, rowoff, cnt, srcs, ae1p, ae2p);
    // ---- layer 1 ----
    k_gemm<41,44><<<dim3((cN+63)/64,2),256,0,stream>>>(x0, W1 + (size_t)i*41*128, h, cN);
    k_anode1<<<cN,64,0,stream>>>(h, as1 + i*128, ad1 + i*128, as_, ad_);
    k_agg1<<<ngrid,256,0,stream>>>(rowoff, srcs, ae1p, cst, i, as_, ad_, h, b1 + i*128, outn);
    // ---- layer 2 ----
    k_gemm<128,128><<<dim3((cN+63)/64,2),256,0,stream>>>(outn, W2 + (size_t)i*128*128, h, cN);
    k_anode2<<<cN,64,0,stream>>>(h, as2 + i*128, ad2 + i*128, as_, ad_);
    k_agg2<<<ngrid,256,0,stream>>>(rowoff, srcs, ae2p, cst, i, as_, ad_, h, b2 + i*128, acc,
                                   pw, pb, es);
  }

  k_pool<<<(cV+VC-1)/VC,512,0,stream>>>(cmask, es, acc, pn, denp);
  k_mlp<<<cR,128,0,stream>>>(acc, pn, denp, Wo1, bo1, Wo2, bo2, Wo3, bo3, out);
}

// Round 7
// 1245.008 us; speedup vs baseline: 2.4341x; 1.0364x over previous
//
#include <hip/hip_runtime.h>
#include <math.h>

// ---------------- problem constants ----------------
constexpr int cN  = 50000;
constexpr int cE  = 600000;
constexpr int cR  = 64;
constexpr int cV  = cN - cR;     // 49936
constexpr int cNF = 9;
constexpr int cIN = 41;          // 9 + 32

// ---------------- const-region sub-offsets (floats) ----------------
constexpr int K_GATES = 0;    // 3
constexpr int K_WTS   = 3;    // 3
constexpr int K_LOOP1 = 6;    // 3*4
constexpr int K_LOOP2 = 18;   // 3
constexpr int K_VE1   = 32;   // 3*8*4
constexpr int K_VE2   = 128;  // 3*8
constexpr int K_EASUM = 160;  // 3*8

// ---------------- ws layout (float units) ----------------
constexpr size_t OFF_X0    = 1024;
constexpr size_t OFF_H     = OFF_X0  + 2050048;   // x0: 50000*41 = 2,050,000 (padded)
constexpr size_t OFF_OUT   = OFF_H   + 6400000;
constexpr size_t OFF_ACC   = OFF_OUT + 6400000;
constexpr size_t OFF_AS    = OFF_ACC + 6400000;   // 200,000
constexpr size_t OFF_AD    = OFF_AS  + 200000;    // 200,000
constexpr size_t OFF_ES    = OFF_AD  + 200000;    // 50,048
constexpr size_t OFF_PN    = OFF_ES  + 50048;     // 8192
constexpr size_t OFF_DENP  = OFF_PN  + 8192;      // 64
constexpr size_t OFF_ROWOFF= OFF_DENP+ 64;        // int cN+1 -> 50,016
constexpr size_t OFF_DEG   = OFF_ROWOFF + 50016;  // int cN
constexpr size_t OFF_CNT   = OFF_DEG + 50000;     // int cN (contiguous with DEG)
constexpr size_t OFF_SRCS  = OFF_CNT + 50000;     // int cE
constexpr size_t OFF_AE1   = OFF_SRCS+ 600000;    // float4 * cE  (16B aligned)
constexpr size_t OFF_AE2   = OFF_AE1 + 2400000;   // float cE
constexpr size_t OFF_BSUM  = OFF_AE2 + 600000;    // int 64
constexpr size_t OFF_BOFF  = OFF_BSUM+ 64;        // int 64
// total ~25.46M floats = ~102 MB

// ---------------- small setup kernels ----------------
__global__ void k_setup(const float* __restrict__ etg, const float* __restrict__ eta,
                        const float* __restrict__ We1, const float* __restrict__ ae1,
                        const float* __restrict__ We2, const float* __restrict__ ae2,
                        float* __restrict__ cst, float* __restrict__ dout){
  int t = threadIdx.x; // 128 threads
  if (t < 3){
    cst[K_GATES+t] = 1.f/(1.f+expf(-etg[t]));
    float m = fmaxf(fmaxf(eta[0],eta[1]),eta[2]);
    float e0=expf(eta[0]-m), e1=expf(eta[1]-m), e2=expf(eta[2]-m);
    cst[K_WTS+t] = expf(eta[t]-m)/(e0+e1+e2);
    dout[1024+t] = eta[t];       // second tuple output
  }
  if (t < 96){ // ve1[(i*8+k)*4+h] = sum_c We1[i,k,h*32+c]*ae1[i,h,c]
    int i = t >> 5, k = (t>>2)&7, h = t&3;
    const float* w = We1 + ((size_t)(i*8+k))*128 + h*32;
    const float* a = ae1 + (i*4+h)*32;
    float s = 0.f;
    for (int c=0;c<32;c++) s += w[c]*a[c];
    cst[K_VE1 + t] = s;
  }
  if (t < 24){ // ve2[i*8+k] = sum_c We2[i,k,c]*ae2[i,c]
    int i = t >> 3, k = t & 7;
    const float* w = We2 + ((size_t)(i*8+k))*128;
    const float* a = ae2 + i*128;
    float s = 0.f;
    for (int c=0;c<128;c++) s += w[c]*a[c];
    cst[K_VE2 + t] = s;
  }
}

// column means of the three ea arrays; 512x3 grid, block-reduced, 8 atomics/block
__global__ __launch_bounds__(256) void k_eamean(const float* __restrict__ ea0,
                         const float* __restrict__ ea1,
                         const float* __restrict__ ea2, float* __restrict__ cst){
  int i = blockIdx.y;
  const float* ea = (i==0)?ea0:(i==1)?ea1:ea2;
  float s[8];
  #pragma unroll
  for (int k=0;k<8;k++) s[k]=0.f;
  for (int e = blockIdx.x*256 + threadIdx.x; e < cE; e += gridDim.x*256){
    const float4* p = (const float4*)(ea + (size_t)e*8);
    float4 a = p[0], b = p[1];
    s[0]+=a.x; s[1]+=a.y; s[2]+=a.z; s[3]+=a.w;
    s[4]+=b.x; s[5]+=b.y; s[6]+=b.z; s[7]+=b.w;
  }
  for (int m=1;m<64;m<<=1){
    #pragma unroll
    for (int k=0;k<8;k++) s[k] += __shfl_xor(s[k], m, 64);
  }
  __shared__ float wsm[4][8];
  int lane = threadIdx.x & 63, wid = threadIdx.x >> 6;
  if (lane == 0){
    #pragma unroll
    for (int k=0;k<8;k++) wsm[wid][k] = s[k];
  }
  __syncthreads();
  if (threadIdx.x < 8){
    float tot = wsm[0][threadIdx.x]+wsm[1][threadIdx.x]+wsm[2][threadIdx.x]+wsm[3][threadIdx.x];
    atomicAdd(&cst[K_EASUM + i*8 + threadIdx.x], tot);
  }
}

__global__ void k_loopconsts(float* __restrict__ cst){
  int t = threadIdx.x;
  if (t < 12){
    int i=t>>2, h=t&3;
    float s=0.f;
    for (int k=0;k<8;k++) s += (cst[K_EASUM+i*8+k]/(float)cE)*cst[K_VE1+(i*8+k)*4+h];
    cst[K_LOOP1+t] = cst[K_GATES+i]*s;
  } else if (t < 15){
    int i=t-12; float s=0.f;
    for (int k=0;k<8;k++) s += (cst[K_EASUM+i*8+k]/(float)cE)*cst[K_VE2+i*8+k];
    cst[K_LOOP2+i] = cst[K_GATES+i]*s;
  }
}

__global__ __launch_bounds__(256) void k_x0(const float* __restrict__ nf, const float* __restrict__ te,
                     const int* __restrict__ nt, float* __restrict__ x0){
  int n = blockIdx.x*4 + (threadIdx.x>>6);
  int j = threadIdx.x & 63;
  if (n >= cN || j >= cIN) return;
  float v = (j < cNF) ? nf[(size_t)n*cNF + j] : te[nt[n]*32 + (j-cNF)];
  x0[(size_t)n*cIN + j] = v;
}

// ---------------- CSR build ----------------
__global__ void k_deg(const int* __restrict__ dst, int* __restrict__ deg){
  int e = blockIdx.x*256 + threadIdx.x;
  if (e < cE) atomicAdd(&deg[dst[e]], 1);
}

__global__ __launch_bounds__(1024) void k_bsum(const int* __restrict__ deg, int* __restrict__ bsum){
  int b=blockIdx.x, t=threadIdx.x, i=b*1024+t;
  int v=(i<cN)?deg[i]:0;
  for(int m=1;m<64;m<<=1) v += __shfl_xor(v,m,64);
  __shared__ int wsm[16];
  if((t&63)==0) wsm[t>>6]=v;
  __syncthreads();
  if(t==0){int s=0; for(int k=0;k<16;k++) s+=wsm[k]; bsum[b]=s;}
}

__global__ void k_bscan(const int* __restrict__ bsum, int* __restrict__ boff){
  int t = threadIdx.x;           // 64 threads, 49 tiles
  int v = (t<49)? bsum[t] : 0;
  int x = v;
  for (int off=1; off<64; off<<=1){
    int y = __shfl_up(x, off, 64);
    if (t>=off) x += y;
  }
  if (t<49) boff[t] = x - v;     // exclusive tile offsets
}

__global__ __launch_bounds__(1024) void k_tilescan(const int* __restrict__ deg,
                        const int* __restrict__ boff, int* __restrict__ rowoff){
  __shared__ int sa[1024], sb[1024];
  int b = blockIdx.x, t = threadIdx.x;
  int i = b*1024 + t;
  int v = (i<cN)? deg[i] : 0;
  sa[t] = v; __syncthreads();
  int* cur = sa; int* nxt = sb;
  for (int off=1; off<1024; off<<=1){
    int x = cur[t];
    if (t>=off) x += cur[t-off];
    nxt[t] = x;
    __syncthreads();
    int* tmp=cur; cur=nxt; nxt=tmp;
  }
  if (i<cN) rowoff[i] = boff[b] + cur[t] - v;   // exclusive
  if (i==cN-1) rowoff[cN] = cE;
}

// fused scatter: CSR placement + per-edge logit consts (ea read once, coalesced)
__global__ void k_scatter(const int* __restrict__ src, const int* __restrict__ dst,
                          const float* __restrict__ ea, const float* __restrict__ cst, int itype,
                          const int* __restrict__ rowoff, int* __restrict__ cnt,
                          int* __restrict__ srcs, float4* __restrict__ ae1p,
                          float* __restrict__ ae2p){
  int e = blockIdx.x*256 + threadIdx.x;
  if (e >= cE) return;
  int d = dst[e];
  int p = rowoff[d] + atomicAdd(&cnt[d], 1);
  srcs[p] = src[e];
  const float4* eap = (const float4*)(ea + (size_t)e*8);
  float4 u = eap[0], v = eap[1];
  float ew[8] = {u.x,u.y,u.z,u.w,v.x,v.y,v.z,v.w};
  float g = cst[K_GATES+itype];
  float a1x=0,a1y=0,a1z=0,a1w=0,a2=0;
  #pragma unroll
  for (int k=0;k<8;k++){
    float evk = ew[k];
    const float* vp = &cst[K_VE1+(itype*8+k)*4];
    a1x += evk*vp[0]; a1y += evk*vp[1]; a1z += evk*vp[2]; a1w += evk*vp[3];
    a2  += evk*cst[K_VE2+itype*8+k];
  }
  ae1p[p] = make_float4(g*a1x, g*a1y, g*a1z, g*a1w);
  ae2p[p] = g*a2;
}

// ---------------- GEMM ----------------
template<int K, int KS>
__global__ __launch_bounds__(256) void k_gemm(const float* __restrict__ A,
                                              const float* __restrict__ B,
                                              float* __restrict__ C, int nrows){
  __shared__ float sA[64][KS];
  __shared__ float sB[K][64];
  const int tid = threadIdx.x;
  const int nb = blockIdx.x * 64;
  const int ch = blockIdx.y;
  for (int idx = tid; idx < 64*K; idx += 256){
    int n = idx / K, k = idx - n*K;
    int row = nb + n; if (row >= nrows) row = nrows - 1;
    sA[n][k] = A[(size_t)row*K + k];
  }
  for (int idx = tid; idx < K*64; idx += 256){
    int k = idx >> 6, c = idx & 63;
    sB[k][c] = B[k*128 + ch*64 + c];
  }
  __syncthreads();
  const int cg = tid & 15, ng = tid >> 4;
  const int c0 = cg*4, n0 = ng*4;
  float acc[4][4] = {};
  int k = 0;
  for (; k + 4 <= K; k += 4){
    float4 a4[4], w4[4];
    #pragma unroll
    for (int ii=0; ii<4; ii++) a4[ii] = *(const float4*)&sA[n0+ii][k];
    #pragma unroll
    for (int kk=0; kk<4; kk++) w4[kk] = *(const float4*)&sB[k+kk][c0];
    const float* ap = (const float*)a4;
    const float* wp = (const float*)w4;
    #pragma unroll
    for (int ii=0; ii<4; ii++)
      #pragma unroll
      for (int kk=0; kk<4; kk++)
        #pragma unroll
        for (int jj=0; jj<4; jj++)
          acc[ii][jj] += ap[ii*4+kk]*wp[kk*4+jj];
  }
  for (; k < K; k++){
    float4 wv = *(const float4*)&sB[k][c0];
    #pragma unroll
    for (int ii=0; ii<4; ii++){
      float a = sA[n0+ii][k];
      acc[ii][0]+=a*wv.x; acc[ii][1]+=a*wv.y; acc[ii][2]+=a*wv.z; acc[ii][3]+=a*wv.w;
    }
  }
  #pragma unroll
  for (int ii=0; ii<4; ii++){
    int row = nb + n0 + ii;
    if (row < nrows){
      float4 v = make_float4(acc[ii][0],acc[ii][1],acc[ii][2],acc[ii][3]);
      *(float4*)&C[(size_t)row*128 + ch*64 + c0] = v;
    }
  }
}

// ---------------- per-node attention logit pieces ----------------
__global__ void k_anode1(const float* __restrict__ h, const float* __restrict__ as_,
                         const float* __restrict__ ad_, float* __restrict__ alphas,
                         float* __restrict__ alphad){
  int n = blockIdx.x, l = threadIdx.x; // 64 threads
  float h0 = h[(size_t)n*128 + l], h1 = h[(size_t)n*128 + 64 + l];
  float s0 = h0*as_[l], s1 = h1*as_[64+l];
  float d0 = h0*ad_[l], d1 = h1*ad_[64+l];
  for (int m=1;m<32;m<<=1){
    s0 += __shfl_xor(s0,m,64); s1 += __shfl_xor(s1,m,64);
    d0 += __shfl_xor(d0,m,64); d1 += __shfl_xor(d1,m,64);
  }
  if ((l&31)==0){
    int hh = l>>5;
    alphas[n*4+hh]   = s0; alphas[n*4+2+hh] = s1;
    alphad[n*4+hh]   = d0; alphad[n*4+2+hh] = d1;
  }
}

__global__ void k_anode2(const float* __restrict__ h, const float* __restrict__ as_,
                         const float* __restrict__ ad_, float* __restrict__ alphas,
                         float* __restrict__ alphad){
  int n = blockIdx.x, l = threadIdx.x;
  float h0 = h[(size_t)n*128+l], h1 = h[(size_t)n*128+64+l];
  float s = h0*as_[l] + h1*as_[64+l];
  float d = h0*ad_[l] + h1*ad_[64+l];
  for (int m=1;m<64;m<<=1){ s += __shfl_xor(s,m,64); d += __shfl_xor(d,m,64); }
  if (l==0){ alphas[n] = s; alphad[n] = d; }
}

// ---------------- fused CSR aggregation, layer 1 (4 heads) ----------------
__global__ __launch_bounds__(256) void k_agg1(
    const int* __restrict__ rowoff, const int* __restrict__ srcs,
    const float4* __restrict__ ae1p,
    const float* __restrict__ cst, int itype,
    const float* __restrict__ alphas, const float* __restrict__ alphad,
    const float* __restrict__ h, const float* __restrict__ b1, float* __restrict__ outn)
{
  int n = blockIdx.x*4 + (threadIdx.x>>6);
  if (n >= cN) return;
  int l = threadIdx.x & 63;
  int hlo = l>>5;          // head of channel l     (0 or 1)
  int hhi = 2 + hlo;       // head of channel l+64  (2 or 3)
  float ad_lo = alphad[n*4+hlo], ad_hi = alphad[n*4+hhi];
  // self-loop contribution
  float a_lo = alphas[n*4+hlo] + ad_lo + cst[K_LOOP1+itype*4+hlo];
  float a_hi = alphas[n*4+hhi] + ad_hi + cst[K_LOOP1+itype*4+hhi];
  a_lo = a_lo>0.f?a_lo:0.2f*a_lo; a_hi = a_hi>0.f?a_hi:0.2f*a_hi;
  float e_lo = expf(a_lo), e_hi = expf(a_hi);
  float den_lo = e_lo, den_hi = e_hi;
  float acc_lo = e_lo * h[(size_t)n*128 + l];
  float acc_hi = e_hi * h[(size_t)n*128 + 64 + l];
  int start = rowoff[n], end = rowoff[n+1];
  for (int cb = start; cb < end; cb += 64){
    int m = min(64, end-cb);
    int md_s = 0; float4 ma = make_float4(0.f,0.f,0.f,0.f);
    if (l < m){ md_s = srcs[cb+l]; ma = ae1p[cb+l]; }
    for (int t=0;t<m;t++){
      int s   = __shfl(md_s, t, 64);
      float ex = __shfl(ma.x, t, 64), ey = __shfl(ma.y, t, 64);
      float ez = __shfl(ma.z, t, 64), ew = __shfl(ma.w, t, 64);
      float ae_lo = hlo ? ey : ex;
      float ae_hi = hlo ? ew : ez;
      float al = alphas[s*4+hlo] + ad_lo + ae_lo;
      float ah = alphas[s*4+hhi] + ad_hi + ae_hi;
      al = al>0.f?al:0.2f*al; ah = ah>0.f?ah:0.2f*ah;
      float elo = expf(al), ehi = expf(ah);
      den_lo += elo; den_hi += ehi;
      acc_lo += elo * h[(size_t)s*128 + l];
      acc_hi += ehi * h[(size_t)s*128 + 64 + l];
    }
  }
  float vlo = acc_lo/(den_lo+1e-16f) + b1[l];
  float vhi = acc_hi/(den_hi+1e-16f) + b1[64+l];
  outn[(size_t)n*128+l]    = vlo>0.f?vlo:expm1f(vlo);   // ELU
  outn[(size_t)n*128+64+l] = vhi>0.f?vhi:expm1f(vhi);
}

// ---------------- fused CSR aggregation, layer 2 (1 head) + pooled scores ----------------
// itype==0 WRITES acc_out (no prior memset needed); itype>0 accumulates.
__global__ __launch_bounds__(256) void k_agg2(
    const int* __restrict__ rowoff, const int* __restrict__ srcs,
    const float* __restrict__ ae2p,
    const float* __restrict__ cst, int itype,
    const float* __restrict__ alphas, const float* __restrict__ alphad,
    const float* __restrict__ h, const float* __restrict__ b2, float* __restrict__ acc_out,
    const float* __restrict__ pw, const float* __restrict__ pb, float* __restrict__ es)
{
  int n = blockIdx.x*4 + (threadIdx.x>>6);
  if (n >= cN) return;
  int l = threadIdx.x & 63;
  float ad = alphad[n];
  float a = alphas[n] + ad + cst[K_LOOP2+itype];
  a = a>0.f?a:0.2f*a;
  float e = expf(a);
  float den = e;
  float acc_lo = e * h[(size_t)n*128 + l];
  float acc_hi = e * h[(size_t)n*128 + 64 + l];
  int start = rowoff[n], end = rowoff[n+1];
  for (int cb = start; cb < end; cb += 64){
    int m = min(64, end-cb);
    int md_s = 0; float ma = 0.f;
    if (l < m){ md_s = srcs[cb+l]; ma = ae2p[cb+l]; }
    for (int t=0;t<m;t++){
      int s   = __shfl(md_s, t, 64);
      float ae = __shfl(ma, t, 64);
      float al = alphas[s] + ad + ae;
      al = al>0.f?al:0.2f*al;
      float el = expf(al);
      den += el;
      acc_lo += el * h[(size_t)s*128 + l];
      acc_hi += el * h[(size_t)s*128 + 64 + l];
    }
  }
  float w = cst[K_WTS+itype];
  size_t o = (size_t)n*128 + l;
  float base_lo = (itype==0) ? 0.f : acc_out[o];
  float base_hi = (itype==0) ? 0.f : acc_out[o+64];
  float nv_lo = base_lo + w*(acc_lo/(den+1e-16f) + b2[l]);
  float nv_hi = base_hi + w*(acc_hi/(den+1e-16f) + b2[64+l]);
  acc_out[o]    = nv_lo;
  acc_out[o+64] = nv_hi;
  if (itype == 2 && n >= cR){
    float s = nv_lo*pw[l] + nv_hi*pw[64+l];
    for (int m=1;m<64;m<<=1) s += __shfl_xor(s,m,64);
    if (l==0) es[n-cR] = expf(s + pb[0]);
  }
}

// ---------------- pooling: pn[64][128] = W[64][V] @ veh[V][128], denp[r]=row-sum ----------------
// 781 blocks x 512 threads; each block owns 64 v's; thread owns 1 channel x 16 r's.
constexpr int VC = 64;
__global__ __launch_bounds__(512) void k_pool(const int* __restrict__ mask,
        const float* __restrict__ es, const float* __restrict__ acc,
        float* __restrict__ pn, float* __restrict__ denp){
  __shared__ float w[64][VC];                  // 16 KB
  int t = threadIdx.x;
  int base = blockIdx.x*VC;
  // stage mask*es: 4096 entries, 8 per thread, coalesced over vv
  #pragma unroll
  for (int k=0;k<8;k++){
    int idx = k*512 + t;
    int r = idx >> 6, vv = idx & 63;
    int v = base + vv;
    float wv = 0.f;
    if (v < cV){ if (mask[(size_t)r*cV + v]) wv = es[v]; }
    w[r][vv] = wv;
  }
  __syncthreads();
  // denp partials: threads < 256, 4 threads per r, skewed cols (conflict-light)
  if (t < 256){
    int rd = t >> 2, seg = t & 3, lane = t & 63;
    float dsum = 0.f;
    #pragma unroll
    for (int j=0;j<16;j++){
      int vv = seg*16 + ((j + lane) & 15);
      dsum += w[rd][vv];
    }
    dsum += __shfl_xor(dsum, 1, 64);
    dsum += __shfl_xor(dsum, 2, 64);
    if (seg == 0) atomicAdd(&denp[rd], dsum);
  }
  // main: thread owns channel c for 16 r's (rh = wave-pair id, uniform per wave)
  int c = t & 127, rh = t >> 7;                // rh in 0..3
  const float* veh = acc + (size_t)cR*128;
  float a[16];
  #pragma unroll
  for (int i2=0;i2<16;i2++) a[i2]=0.f;
  #pragma unroll 4
  for (int vv=0; vv<VC; vv+=4){
    int v0 = base + vv;
    int vl0 = min(v0+0, cV-1), vl1 = min(v0+1, cV-1);
    int vl2 = min(v0+2, cV-1), vl3 = min(v0+3, cV-1);
    float h0 = veh[(size_t)vl0*128 + c];
    float h1 = veh[(size_t)vl1*128 + c];
    float h2 = veh[(size_t)vl2*128 + c];
    float h3 = veh[(size_t)vl3*128 + c];
    #pragma unroll
    for (int rr=0; rr<16; rr++){
      float4 w4 = *(const float4*)&w[rh*16+rr][vv];   // wave-uniform broadcast
      a[rr] += w4.x*h0 + w4.y*h1 + w4.z*h2 + w4.w*h3;
    }
  }
  #pragma unroll
  for (int rr=0; rr<16; rr++)
    atomicAdd(&pn[(rh*16+rr)*128 + c], a[rr]);
}

// ---------------- head MLP ----------------
__global__ __launch_bounds__(128) void k_mlp(const float* __restrict__ acc, const float* __restrict__ pn,
                     const float* __restrict__ denp,
                     const float* __restrict__ Wo1, const float* __restrict__ bo1,
                     const float* __restrict__ Wo2, const float* __restrict__ bo2,
                     const float* __restrict__ Wo3, const float* __restrict__ bo3,
                     float* __restrict__ dout){
  __shared__ float comb[256], q1[128], q2[64];
  int r = blockIdx.x, t = threadIdx.x;
  comb[t] = acc[(size_t)r*128 + t];
  float dp = denp[r];
  comb[128+t] = dp > 0.f ? pn[r*128+t]/dp : 0.f;
  __syncthreads();
  float s = bo1[t];
  for (int k=0;k<256;k++) s += comb[k]*Wo1[k*128+t];
  q1[t] = fmaxf(s, 0.f);
  __syncthreads();
  if (t < 64){
    float s2 = bo2[t];
    for (int k=0;k<128;k++) s2 += q1[k]*Wo2[k*64+t];
    q2[t] = fmaxf(s2, 0.f);
  }
  __syncthreads();
  if (t < 16){
    float s3 = bo3[t];
    for (int k=0;k<64;k++) s3 += q2[k]*Wo3[k*16+t];
    dout[r*16+t] = s3;
  }
}

// ---------------- launcher ----------------
extern "C" void kernel_launch(void* const* d_in, const int* in_sizes, int n_in,
                              void* d_out, int out_size, void* d_ws, size_t ws_size,
                              hipStream_t stream){
  const float* nf   = (const float*)d_in[0];
  const float* ea[3]= {(const float*)d_in[1],(const float*)d_in[2],(const float*)d_in[3]};
  const float* te   = (const float*)d_in[4];
  const float* etg  = (const float*)d_in[5];
  const float* eta  = (const float*)d_in[6];
  const float* W1   = (const float*)d_in[7];
  const float* as1  = (const float*)d_in[8];
  const float* ad1  = (const float*)d_in[9];
  const float* We1  = (const float*)d_in[10];
  const float* ae1  = (const float*)d_in[11];
  const float* b1   = (const float*)d_in[12];
  const float* W2   = (const float*)d_in[13];
  const float* as2  = (const float*)d_in[14];
  const float* ad2  = (const float*)d_in[15];
  const float* We2  = (const float*)d_in[16];
  const float* ae2  = (const float*)d_in[17];
  const float* b2   = (const float*)d_in[18];
  const float* pw   = (const float*)d_in[19];
  const float* pb   = (const float*)d_in[20];
  const float* Wo1  = (const float*)d_in[21];
  const float* bo1  = (const float*)d_in[22];
  const float* Wo2  = (const float*)d_in[23];
  const float* bo2  = (const float*)d_in[24];
  const float* Wo3  = (const float*)d_in[25];
  const float* bo3  = (const float*)d_in[26];
  const int*  nt    = (const int*)d_in[27];
  const int*  ei[3] = {(const int*)d_in[28],(const int*)d_in[29],(const int*)d_in[30]};
  const int*  cmask = (const int*)d_in[31];

  float* ws  = (float*)d_ws;
  float* out = (float*)d_out;

  float* cst  = ws;
  float* x0   = ws + OFF_X0;
  float* h    = ws + OFF_H;
  float* outn = ws + OFF_OUT;
  float* acc  = ws + OFF_ACC;
  float* as_  = ws + OFF_AS;
  float* ad_  = ws + OFF_AD;
  float* es   = ws + OFF_ES;
  float* pn   = ws + OFF_PN;
  float* denp = ws + OFF_DENP;
  int* rowoff = (int*)(ws + OFF_ROWOFF);
  int* deg    = (int*)(ws + OFF_DEG);
  int* cnt    = (int*)(ws + OFF_CNT);
  int* srcs   = (int*)(ws + OFF_SRCS);
  float4* ae1p= (float4*)(ws + OFF_AE1);
  float* ae2p = ws + OFF_AE2;
  int* bsum   = (int*)(ws + OFF_BSUM);
  int* boff   = (int*)(ws + OFF_BOFF);

  hipMemsetAsync(cst, 0, 1024*sizeof(float), stream);
  hipMemsetAsync(pn,  0, ((size_t)cR*128 + cR)*sizeof(float), stream);

  k_setup<<<1,128,0,stream>>>(etg, eta, We1, ae1, We2, ae2, cst, out);
  k_eamean<<<dim3(512,3),256,0,stream>>>(ea[0],ea[1],ea[2],cst);
  k_loopconsts<<<1,16,0,stream>>>(cst);
  k_x0<<<(cN+3)/4,256,0,stream>>>(nf, te, nt, x0);

  const int egrid = (cE+255)/256;
  const int ngrid = (cN+3)/4;
  const int ntile = (cN+1023)/1024;   // 49

  for (int i=0;i<3;i++){
    const int* src = ei[i];
    const int* dst = ei[i] + cE;
    // ---- CSR build (shared by both layers of this type) ----
    hipMemsetAsync(deg, 0, (size_t)2*cN*sizeof(int), stream);   // deg + cnt contiguous
    k_deg<<<egrid,256,0,stream>>>(dst, deg);
    k_bsum<<<ntile,1024,0,stream>>>(deg, bsum);
    k_bscan<<<1,64,0,stream>>>(bsum, boff);
    k_tilescan<<<ntile,1024,0,stream>>>(deg, boff, rowoff);
    k_scatter<<<egrid,256,0,stream>>>(src, dst, ea[i], cst, i, rowoff, cnt, srcs, ae1p, ae2p);
    // ---- layer 1 ----
    k_gemm<41,44><<<dim3((cN+63)/64,2),256,0,stream>>>(x0, W1 + (size_t)i*41*128, h, cN);
    k_anode1<<<cN,64,0,stream>>>(h, as1 + i*128, ad1 + i*128, as_, ad_);
    k_agg1<<<ngrid,256,0,stream>>>(rowoff, srcs, ae1p, cst, i, as_, ad_, h, b1 + i*128, outn);
    // ---- layer 2 ----
    k_gemm<128,128><<<dim3((cN+63)/64,2),256,0,stream>>>(outn, W2 + (size_t)i*128*128, h, cN);
    k_anode2<<<cN,64,0,stream>>>(h, as2 + i*128, ad2 + i*128, as_, ad_);
    k_agg2<<<ngrid,256,0,stream>>>(rowoff, srcs, ae2p, cst, i, as_, ad_, h, b2 + i*128, acc,
                                   pw, pb, es);
  }

  k_pool<<<(cV+VC-1)/VC,512,0,stream>>>(cmask, es, acc, pn, denp);
  k_mlp<<<cR,128,0,stream>>>(acc, pn, denp, Wo1, bo1, Wo2, bo2, Wo3, bo3, out);
}